// Round 2
// baseline (242.957 us; speedup 1.0000x reference)
//
#include <hip/hip_runtime.h>
#include <type_traits>

#define NODE 400
#define POP 3
#define TRS 40
#define STEPS 10
#define DMAX 500
#define OUT 64
#define DT 0.1f
#define JPL 7           // ceil(NODE/64) j-indices per lane
#define WSTR 512        // per-stream W bin stride (delta in [0,511])

__device__ __forceinline__ float relu_(float x) { return x > 0.f ? x : 0.f; }
__device__ __forceinline__ float rcp_(float x) { return __builtin_amdgcn_rcpf(x); }
__device__ __forceinline__ float rlane_(float v, int l) {
  return __builtin_bit_cast(float, __builtin_amdgcn_readlane(__builtin_bit_cast(int, v), l));
}

// ---- DPP helpers
template <int CTRL>
__device__ __forceinline__ float dpp_mov(float x) {
  int r = __builtin_amdgcn_update_dpp(0, __builtin_bit_cast(int, x), CTRL,
                                      0xf, 0xf, true);
  return __builtin_bit_cast(float, r);
}
template <int CTRL>
__device__ __forceinline__ int dpp_movi(int x) {
  return __builtin_amdgcn_update_dpp(0, x, CTRL, 0xf, 0xf, true);
}
// wave rotate: dst[L] = src[(L+1) & 63]  (wave_rol:1 = 0x134, verified r1)
__device__ __forceinline__ float wrol1(float x) { return dpp_mov<0x134>(x); }

__device__ __forceinline__ void wave_reduce3(float& a, float& b, float& c) {
  a += dpp_mov<0x111>(a); b += dpp_mov<0x111>(b); c += dpp_mov<0x111>(c);
  a += dpp_mov<0x112>(a); b += dpp_mov<0x112>(b); c += dpp_mov<0x112>(c);
  a += dpp_mov<0x114>(a); b += dpp_mov<0x114>(b); c += dpp_mov<0x114>(c);
  a += dpp_mov<0x118>(a); b += dpp_mov<0x118>(b); c += dpp_mov<0x118>(c);
  a += dpp_mov<0x142>(a); b += dpp_mov<0x142>(b); c += dpp_mov<0x142>(c);
  a += dpp_mov<0x143>(a); b += dpp_mov<0x143>(b); c += dpp_mov<0x143>(c);
  a = rlane_(a, 63); b = rlane_(b, 63); c = rlane_(c, 63);
}

__device__ __forceinline__ int wave_max_int(int x) {
  x = max(x, dpp_movi<0x111>(x));
  x = max(x, dpp_movi<0x112>(x));
  x = max(x, dpp_movi<0x114>(x));
  x = max(x, dpp_movi<0x118>(x));
  x = max(x, dpp_movi<0x142>(x));
  x = max(x, dpp_movi<0x143>(x));
  return __builtin_amdgcn_readlane(x, 63);
}

// ---------------------------------------------------------------------------
// Kernel A: Frobenius sum-of-squares partials (64 blocks, no atomics).
// ---------------------------------------------------------------------------
__global__ __launch_bounds__(256) void ssq_kernel(
    const float* __restrict__ wbb, const float* __restrict__ wff,
    const float* __restrict__ wll, const float* __restrict__ sc,
    float* __restrict__ part) {
  float eb = 0.f, ef = 0.f, el = 0.f;
  for (int idx = blockIdx.x * 256 + threadIdx.x; idx < NODE * NODE;
       idx += 64 * 256) {
    int i = idx / NODE, j = idx - i * NODE;
    int ji = j * NODE + i;
    float scij = sc[idx];
    float b = expf(wbb[idx]) * scij;
    float f = expf(wff[idx]) * scij;
    float l = 0.5f * (expf(wll[idx]) * scij + expf(wll[ji]) * sc[ji]);
    eb = fmaf(b, b, eb); ef = fmaf(f, f, ef); el = fmaf(l, l, el);
  }
  wave_reduce3(eb, ef, el);
  __shared__ float red[3][4];
  int lane = threadIdx.x & 63, wv = threadIdx.x >> 6;
  if (lane == 0) { red[0][wv] = eb; red[1][wv] = ef; red[2][wv] = el; }
  __syncthreads();
  if (threadIdx.x == 0) {
    part[blockIdx.x]       = red[0][0] + red[0][1] + red[0][2] + red[0][3];
    part[64 + blockIdx.x]  = red[1][0] + red[1][1] + red[1][2] + red[1][3];
    part[128 + blockIdx.x] = red[2][0] + red[2][1] + red[2][2] + red[2][3];
  }
}

// ---------------------------------------------------------------------------
// Kernel B: per-node simulation, TWO nodes per wave (ILP fills latency gaps),
// INTERLEAVED ring layout: slot s lives at lane s/NR, reg s%NR.
// Rotation by 1 = register rename (reg r <- reg r+1, same lane, folded into
// the scatter fma) + one DPP wave_rol for the top reg (lane63 zero-filled).
// Harvest is always readlane(P0, 0). Packed transcendentals: lanes 0-5 node A,
// lanes 6-11 node B -> ONE exp2 + ONE rcp per step for both nodes.
// ---------------------------------------------------------------------------
__global__ __launch_bounds__(64) void sim_kernel(
    const float* __restrict__ external, const float* __restrict__ hx,
    const float* __restrict__ hE, const float* __restrict__ sc,
    const float* __restrict__ dist, const float* __restrict__ wbb,
    const float* __restrict__ wff, const float* __restrict__ wll,
    const float* __restrict__ theta, const float* __restrict__ part,
    float* __restrict__ vsnap) {
  const int nodeA = blockIdx.x * 2;
  const int nodeB = nodeA + 1;
  const int lane = threadIdx.x;

  __shared__ float Wall[2][3 * WSTR];   // per node: Wl | Wf | Wb delay bins
  __shared__ float hE_lds[2][DMAX];
  __shared__ float u_lds[2][STEPS * TRS];

  // --- global norm sums from ssq partials (one DPP reduce) ---
  float sb = part[lane], sf = part[64 + lane], sl = part[128 + lane];
  wave_reduce3(sb, sf, sl);
  const float inv_nb = 1.f / sqrtf(sb);
  const float inv_nf = 1.f / sqrtf(sf);
  const float inv_nl = 1.f / sqrtf(sl);

  // --- parameters ---
  const float VL = relu_(theta[0]), VI = relu_(theta[1]);
  const float VE = relu_(theta[2]), VNMDA = relu_(theta[3]);
  const float alpha_mg = relu_(theta[4]), VR = relu_(theta[5]);
  const float pi_sigma = relu_(theta[6]);
  const float gLp = relu_(theta[7]), Cc = relu_(theta[8]), kappa = relu_(theta[9]);
  const float g_gE = relu_(theta[10]), g_gE_sc = relu_(theta[11]);
  const float g_gI = relu_(theta[12]), g_gI_sc = relu_(theta[13]);
  const float g_gN = relu_(theta[14]), g_gN_sc = relu_(theta[15]);
  const float g_k = relu_(theta[16]);
  const float mu = 0.1f + relu_(theta[20]);
  const float uk = relu_(theta[21]) * theta[23];
  const float g_l = relu_(theta[24]), g_f = relu_(theta[25]), g_b = relu_(theta[26]);
  const float DTC = DT / Cc;
  const float dk = DT * kappa;
  const float nps = -pi_sigma, psVR = pi_sigma * VR;
  const float nam = -alpha_mg;

  const float dk1  = 1.f - dk;
  const float cA   = dk * g_l;
  const float cF   = dk * g_f;
  const float cB   = dk * g_b;
  const float cE0s = dk * g_gE;
  const float cE1e = dk * g_gE_sc;
  const float cE2e = dk * g_k;
  const float cI0  = dk * g_gI;
  const float cI1  = dk * g_gI_sc;
  const float cN0s = dk * g_gN;
  const float cN1  = dk * g_gN_sc;
  const float cN2  = dk * g_gN;
  const float gLVL = gLp * VL;

  // --- stage LDS ---
  {
    float* wflat = &Wall[0][0];
    for (int k = lane; k < 2 * 3 * WSTR; k += 64) wflat[k] = 0.f;
  }
  for (int d = lane; d < DMAX; d += 64) {
    hE_lds[0][d] = hE[nodeA * DMAX + d];
    hE_lds[1][d] = hE[nodeB * DMAX + d];
  }
  const float ukdk = dk * uk;
  for (int t = lane; t < STEPS * TRS; t += 64) {
    u_lds[0][t] = ukdk * external[nodeA * STEPS * TRS + t];
    u_lds[1][t] = ukdk * external[nodeB * STEPS * TRS + t];
  }

  // --- bin weights by delay (LDS float atomics), row sums, max delay ---
  float rlA = 0.f, rfA = 0.f, rbA = 0.f;
  float rlB = 0.f, rfB = 0.f, rbB = 0.f;
  int mymax = 0;
#pragma unroll
  for (int kj = 0; kj < JPL; ++kj) {
    int j = lane + kj * 64;
    if (j < NODE) {
      {
        int ij = nodeA * NODE + j, ji = j * NODE + nodeA;
        float scij = sc[ij];
        float vb = expf(wbb[ij]) * scij * inv_nb;
        float vf = expf(wff[ij]) * scij * inv_nf;
        float vl = 0.5f * (expf(wll[ij]) * scij + expf(wll[ji]) * sc[ji]) * inv_nl;
        int dd = (int)(dist[ij] / mu);
        dd = min(max(dd, 0), DMAX - 1);
        atomicAdd(&Wall[0][dd], vl);
        atomicAdd(&Wall[0][WSTR + dd], vf);
        atomicAdd(&Wall[0][2 * WSTR + dd], vb);
        rlA += vl; rfA += vf; rbA += vb;
        mymax = max(mymax, dd);
      }
      {
        int ij = nodeB * NODE + j, ji = j * NODE + nodeB;
        float scij = sc[ij];
        float vb = expf(wbb[ij]) * scij * inv_nb;
        float vf = expf(wff[ij]) * scij * inv_nf;
        float vl = 0.5f * (expf(wll[ij]) * scij + expf(wll[ji]) * sc[ji]) * inv_nl;
        int dd = (int)(dist[ij] / mu);
        dd = min(max(dd, 0), DMAX - 1);
        atomicAdd(&Wall[1][dd], vl);
        atomicAdd(&Wall[1][WSTR + dd], vf);
        atomicAdd(&Wall[1][2 * WSTR + dd], vb);
        rlB += vl; rfB += vf; rbB += vb;
        mymax = max(mymax, dd);
      }
    }
  }
  wave_reduce3(rlA, rfA, rbA);
  wave_reduce3(rlB, rfB, rbB);
  const int maxd = wave_max_int(mymax);

  // per-node sP coefficients (lr row-sum terms folded)
  const float cE0s2A = cE0s - cA * rlA, cE0s2B = cE0s - cA * rlB;
  const float cN0s2A = cN0s - cA * rlA, cN0s2B = cN0s - cA * rlB;
  const float cE1sA = -cB * rbA, cE1sB = -cB * rbB;
  const float cE2sA = -cF * rfA, cE2sB = -cF * rfB;

  // --- initial state (replicated across lanes) ---
  const int hbA = nodeA * POP * 4, hbB = nodeB * POP * 4;
  float V0a = hx[hbA + 0], V1a = hx[hbA + 4], V2a = hx[hbA + 8];
  float E0a = hx[hbA + 1], E1a = hx[hbA + 5], E2a = hx[hbA + 9];
  float I0a = hx[hbA + 2], I1a = hx[hbA + 6], I2a = hx[hbA + 10];
  float N0a = hx[hbA + 3], N1a = hx[hbA + 7], N2a = hx[hbA + 11];
  float V0b = hx[hbB + 0], V1b = hx[hbB + 4], V2b = hx[hbB + 8];
  float E0b = hx[hbB + 1], E1b = hx[hbB + 5], E2b = hx[hbB + 9];
  float I0b = hx[hbB + 2], I1b = hx[hbB + 6], I2b = hx[hbB + 10];
  float N0b = hx[hbB + 3], N1b = hx[hbB + 7], N2b = hx[hbB + 11];

  // --- packed-transcendental lane constants: lanes 0-5 node A, 6-11 node B;
  // within each 6: 0-2 sigmoid args (V0,V1,V2), 3-5 mN exp args (V0,V1,V2).
  const float L2E = 1.44269504088896f;
  const int l6 = lane % 6;
  const bool loS = (l6 < 3);
  const float caL = loS ? nps * L2E : nam * L2E;
  const float cbL = loS ? psVR * L2E : 0.f;
  const float cdL = loS ? 1.f : 0.2f;
  const bool selB = (l6 == 1) || (l6 == 4);
  const bool selC = (l6 == 2) || (l6 == 5);
  const bool isBn = (lane >= 6);
  const bool is63 = (lane == 63);

  // --- shared-constant dynamics update (per node) ---
  auto dyn = [&](float& V0, float& V1, float& V2, float& E0, float& E1,
                 float& E2, float& I0, float& I1, float& I2, float& N0,
                 float& N1, float& N2, float sE, float sI, float sP, float m0,
                 float m1, float m2, float al, float af, float ab, float U,
                 float cE0s2, float cN0s2, float cE1s, float cE2s) {
    float t1 = cA * al, t2 = cF * af, t3 = cB * ab;
    float nE0 = fmaf(dk1, E0, fmaf(cE0s2, sP, t1 + U));
    float nE1 = fmaf(dk1, E1, fmaf(cE1e, sE, fmaf(cE1s, sP, t3)));
    float nE2 = fmaf(dk1, E2, fmaf(cE2e, sE, fmaf(cE2s, sP, t2 + U)));
    float pI = cI0 * sI;
    float nI0 = fmaf(dk1, I0, pI);
    float nI1 = fmaf(dk1, I1, cI1 * sI);
    float nI2 = fmaf(dk1, I2, pI);
    float nN0 = fmaf(dk1, N0, fmaf(cN0s2, sP, t1));
    float nN1 = fmaf(dk1, N1, cN1 * sE);
    float nN2 = fmaf(dk1, N2, cN2 * sE);

    float Nm0 = N0 * m0, Nm1 = N1 * m1, Nm2 = N2 * m2;
    float R0 = fmaf(E0, VE, fmaf(Nm0, VNMDA, fmaf(I0, -VI, -gLVL)));
    float R1 = fmaf(E1, VE, fmaf(Nm1, VNMDA, fmaf(I1, -VI, -gLVL)));
    float R2 = fmaf(E2, VE, fmaf(Nm2, VNMDA, fmaf(I2, -VI, -gLVL)));
    float S0 = gLp + E0 + I0 + Nm0;
    float S1 = gLp + E1 + I1 + Nm1;
    float S2 = gLp + E2 + I2 + Nm2;
    V0 = fmaf(DTC, fmaf(-S0, V0, R0), V0);
    V1 = fmaf(DTC, fmaf(-S1, V1, R1), V1);
    V2 = fmaf(DTC, fmaf(-S2, V2, R2), V2);
    E0 = nE0; E1 = nE1; E2 = nE2;
    I0 = nI0; I1 = nI1; I2 = nI2;
    N0 = nN0; N1 = nN1; N2 = nN2;
  };

  auto core = [&](auto nrtag) {
    constexpr int NR = decltype(nrtag)::value;
    // Ring capacity 64*NR slots; top slot weight must be 0 (maxd <= 64*NR-2).

    // --- static per-lane weights: reg r lane L = Wbins[NR*L + r] ---
    float WlA[NR], WfA[NR], WbA[NR], WlB[NR], WfB[NR], WbB[NR];
#pragma unroll
    for (int r = 0; r < NR; ++r) {
      int s = NR * lane + r;
      WlA[r] = Wall[0][s];
      WfA[r] = Wall[0][WSTR + s];
      WbA[r] = Wall[0][2 * WSTR + s];
      WlB[r] = Wall[1][s];
      WfB[r] = Wall[1][WSTR + s];
      WbB[r] = Wall[1][2 * WSTR + s];
    }

    // --- prologue: P[slot s] = sum_{d >= s} W[d] * hE[d - s].
    // hbuf[r] holds hE[(d - r) - NR*lane] (0 when index < 0).
    float PlA[NR], PfA[NR], PbA[NR], PlB[NR], PfB[NR], PbB[NR];
    float hbufA[NR], hbufB[NR];
#pragma unroll
    for (int r = 0; r < NR; ++r) {
      PlA[r] = 0.f; PfA[r] = 0.f; PbA[r] = 0.f;
      PlB[r] = 0.f; PfB[r] = 0.f; PbB[r] = 0.f;
      hbufA[r] = 0.f; hbufB[r] = 0.f;
    }
    for (int d = 0; d <= maxd; ++d) {
      float wlA_ = Wall[0][d], wfA_ = Wall[0][WSTR + d], wbA_ = Wall[0][2 * WSTR + d];
      float wlB_ = Wall[1][d], wfB_ = Wall[1][WSTR + d], wbB_ = Wall[1][2 * WSTR + d];
#pragma unroll
      for (int r = NR - 1; r > 0; --r) { hbufA[r] = hbufA[r - 1]; hbufB[r] = hbufB[r - 1]; }
      int idx = d - NR * lane;
      bool ok = idx >= 0;
      int ci = ok ? idx : 0;
      float hA = hE_lds[0][ci]; hA = ok ? hA : 0.f;
      float hB = hE_lds[1][ci]; hB = ok ? hB : 0.f;
      hbufA[0] = hA; hbufB[0] = hB;
#pragma unroll
      for (int r = 0; r < NR; ++r) {
        PlA[r] = fmaf(wlA_, hbufA[r], PlA[r]);
        PfA[r] = fmaf(wfA_, hbufA[r], PfA[r]);
        PbA[r] = fmaf(wbA_, hbufA[r], PbA[r]);
        PlB[r] = fmaf(wlB_, hbufB[r], PlB[r]);
        PfB[r] = fmaf(wfB_, hbufB[r], PfB[r]);
        PbB[r] = fmaf(wbB_, hbufB[r], PbB[r]);
      }
    }

    // rotate-by-1 (rename + 1 dpp) fused with scatter: after harvest of slot 0,
    // new P[r] = old P[r+1] + W[r]*sP ; new P[NR-1] = (shift-in 0) + W[NR-1]*sP
    auto rotscat = [&](float* P, const float* W, float sPv) {
      float nl = is63 ? 0.f : wrol1(P[0]);
#pragma unroll
      for (int r = 0; r < NR - 1; ++r) P[r] = fmaf(W[r], sPv, P[r + 1]);
      P[NR - 1] = fmaf(W[NR - 1], sPv, nl);
    };

    for (int tr = 0; tr < TRS; ++tr) {
      float uA = (lane < STEPS) ? u_lds[0][lane * TRS + tr] : 0.f;
      float uB = (lane < STEPS) ? u_lds[1][lane * TRS + tr] : 0.f;
#pragma unroll
      for (int st = 0; st < STEPS; ++st) {
        // 1) harvest al/af/ab for both nodes: slot 0 = reg 0, lane 0
        float alA = rlane_(PlA[0], 0);
        float afA = rlane_(PfA[0], 0);
        float abA = rlane_(PbA[0], 0);
        float alB = rlane_(PlB[0], 0);
        float afB = rlane_(PfB[0], 0);
        float abB = rlane_(PbB[0], 0);

        // 2) packed sigmoid + mN: ONE v_exp + ONE v_rcp for all 12 values
        float VsA_ = selC ? V2a : (selB ? V1a : V0a);
        float VsB_ = selC ? V2b : (selB ? V1b : V0b);
        float Vs = isBn ? VsB_ : VsA_;
        float ex = __builtin_amdgcn_exp2f(fmaf(caL, Vs, cbL));
        float sg = rcp_(fmaf(cdL, ex, 1.f));
        float sEa = rlane_(sg, 0), sIa = rlane_(sg, 1), sPa = rlane_(sg, 2);
        float m0a = rlane_(sg, 3), m1a = rlane_(sg, 4), m2a = rlane_(sg, 5);
        float sEb = rlane_(sg, 6), sIb = rlane_(sg, 7), sPb = rlane_(sg, 8);
        float m0b = rlane_(sg, 9), m1b = rlane_(sg, 10), m2b = rlane_(sg, 11);
        float Ua = rlane_(uA, st);
        float Ub = rlane_(uB, st);

        // 3) dynamics, both nodes (independent strands -> ILP)
        dyn(V0a, V1a, V2a, E0a, E1a, E2a, I0a, I1a, I2a, N0a, N1a, N2a,
            sEa, sIa, sPa, m0a, m1a, m2a, alA, afA, abA, Ua,
            cE0s2A, cN0s2A, cE1sA, cE2sA);
        dyn(V0b, V1b, V2b, E0b, E1b, E2b, I0b, I1b, I2b, N0b, N1b, N2b,
            sEb, sIb, sPb, m0b, m1b, m2b, alB, afB, abB, Ub,
            cE0s2B, cN0s2B, cE1sB, cE2sB);

        // 4) rotate + scatter (1 dpp + 1 cnd + NR fma per stream per node)
        rotscat(PlA, WlA, sPa);
        rotscat(PfA, WfA, sPa);
        rotscat(PbA, WbA, sPa);
        rotscat(PlB, WlB, sPb);
        rotscat(PfB, WfB, sPb);
        rotscat(PbB, WbB, sPb);
      }
      if (lane == 0) {
        vsnap[tr * NODE + nodeA] = V2a;
        vsnap[tr * NODE + nodeB] = V2b;
      }
    }
  };

  if (maxd <= 126) core(std::integral_constant<int, 2>{});
  else             core(std::integral_constant<int, 8>{});
}

// ---------------------------------------------------------------------------
// Kernel C: EEG readout, 4 waves split the n-dimension.
// ---------------------------------------------------------------------------
__global__ __launch_bounds__(256) void eeg_kernel(
    const float* __restrict__ lm, const float* __restrict__ vsnap,
    const float* __restrict__ theta, float* __restrict__ out) {
  int tr = blockIdx.x;
  __shared__ float cm[NODE];
  __shared__ float vs[NODE];
  __shared__ float partl[4][OUT];
  int tid = threadIdx.x;
  for (int n = tid; n < NODE; n += 256) {
    float s = 0.f;
    for (int o = 0; o < OUT; ++o) s += lm[o * NODE + n];
    cm[n] = s * (1.f / OUT);
    vs[n] = vsnap[tr * NODE + n];
  }
  __syncthreads();
  int o = tid & 63, w = tid >> 6;
  float acc = 0.f;
  for (int n = w * 100; n < w * 100 + 100; ++n)
    acc = fmaf(lm[o * NODE + n] - cm[n], vs[n], acc);
  partl[w][o] = acc;
  __syncthreads();
  if (tid < OUT) {
    float cy0 = theta[22], y0 = theta[19];
    out[tr * OUT + tid] =
        cy0 * (partl[0][tid] + partl[1][tid] + partl[2][tid] + partl[3][tid]) - y0;
  }
}

extern "C" void kernel_launch(void* const* d_in, const int* in_sizes, int n_in,
                              void* d_out, int out_size, void* d_ws, size_t ws_size,
                              hipStream_t stream) {
  const float* external = (const float*)d_in[0];
  const float* hx       = (const float*)d_in[1];
  const float* hE       = (const float*)d_in[2];
  const float* sc       = (const float*)d_in[3];
  const float* dist     = (const float*)d_in[4];
  const float* wbb      = (const float*)d_in[5];
  const float* wff      = (const float*)d_in[6];
  const float* wll      = (const float*)d_in[7];
  const float* lm       = (const float*)d_in[8];
  const float* theta    = (const float*)d_in[9];
  float* out = (float*)d_out;

  float* vsnap = (float*)d_ws;               // TRS*NODE
  float* part  = vsnap + TRS * NODE;         // 3*64 ssq partials

  ssq_kernel<<<64, 256, 0, stream>>>(wbb, wff, wll, sc, part);
  sim_kernel<<<NODE / 2, 64, 0, stream>>>(external, hx, hE, sc, dist, wbb, wff,
                                          wll, theta, part, vsnap);
  eeg_kernel<<<TRS, 256, 0, stream>>>(lm, vsnap, theta, out);
}

// Round 3
// 194.989 us; speedup vs baseline: 1.2460x; 1.2460x over previous
//
#include <hip/hip_runtime.h>
#include <type_traits>

#define NODE 400
#define POP 3
#define TRS 40
#define STEPS 10
#define DMAX 500
#define OUT 64
#define DT 0.1f
#define JPL 7           // ceil(NODE/64) j-indices per lane
#define WSTR 512        // per-stream W bin stride (delta in [0,511])

__device__ __forceinline__ float relu_(float x) { return x > 0.f ? x : 0.f; }
__device__ __forceinline__ float rcp_(float x) { return __builtin_amdgcn_rcpf(x); }
__device__ __forceinline__ float rlane_(float v, int l) {
  return __builtin_bit_cast(float, __builtin_amdgcn_readlane(__builtin_bit_cast(int, v), l));
}
// broadcast lane 0 to all lanes, result in VGPR (not SGPR) -> legal as the
// "second scalar" in ops that also read an SGPR constant.
__device__ __forceinline__ float bperm0_(float v) {
  return __builtin_bit_cast(float,
      __builtin_amdgcn_ds_bpermute(0, __builtin_bit_cast(int, v)));
}
// pin a value into a VGPR (kills compiler SGPR-materialization movs per use)
#define PIN_V(x) asm volatile("" : "+v"(x))

// ---- DPP helpers
template <int CTRL>
__device__ __forceinline__ float dpp_mov(float x) {
  int r = __builtin_amdgcn_update_dpp(0, __builtin_bit_cast(int, x), CTRL,
                                      0xf, 0xf, true);
  return __builtin_bit_cast(float, r);
}
template <int CTRL>
__device__ __forceinline__ int dpp_movi(int x) {
  return __builtin_amdgcn_update_dpp(0, x, CTRL, 0xf, 0xf, true);
}
// wave rotate: dst[L] = src[(L+1) & 63]  (wave_rol:1 = 0x134, verified r1/r2)
__device__ __forceinline__ float wrol1(float x) { return dpp_mov<0x134>(x); }

__device__ __forceinline__ void wave_reduce3(float& a, float& b, float& c) {
  a += dpp_mov<0x111>(a); b += dpp_mov<0x111>(b); c += dpp_mov<0x111>(c);
  a += dpp_mov<0x112>(a); b += dpp_mov<0x112>(b); c += dpp_mov<0x112>(c);
  a += dpp_mov<0x114>(a); b += dpp_mov<0x114>(b); c += dpp_mov<0x114>(c);
  a += dpp_mov<0x118>(a); b += dpp_mov<0x118>(b); c += dpp_mov<0x118>(c);
  a += dpp_mov<0x142>(a); b += dpp_mov<0x142>(b); c += dpp_mov<0x142>(c);
  a += dpp_mov<0x143>(a); b += dpp_mov<0x143>(b); c += dpp_mov<0x143>(c);
  a = rlane_(a, 63); b = rlane_(b, 63); c = rlane_(c, 63);
}

__device__ __forceinline__ int wave_max_int(int x) {
  x = max(x, dpp_movi<0x111>(x));
  x = max(x, dpp_movi<0x112>(x));
  x = max(x, dpp_movi<0x114>(x));
  x = max(x, dpp_movi<0x118>(x));
  x = max(x, dpp_movi<0x142>(x));
  x = max(x, dpp_movi<0x143>(x));
  return __builtin_amdgcn_readlane(x, 63);
}

// ---------------------------------------------------------------------------
// Kernel A: Frobenius sum-of-squares partials (64 blocks, no atomics).
// ---------------------------------------------------------------------------
__global__ __launch_bounds__(256) void ssq_kernel(
    const float* __restrict__ wbb, const float* __restrict__ wff,
    const float* __restrict__ wll, const float* __restrict__ sc,
    float* __restrict__ part) {
  float eb = 0.f, ef = 0.f, el = 0.f;
  for (int idx = blockIdx.x * 256 + threadIdx.x; idx < NODE * NODE;
       idx += 64 * 256) {
    int i = idx / NODE, j = idx - i * NODE;
    int ji = j * NODE + i;
    float scij = sc[idx];
    float b = expf(wbb[idx]) * scij;
    float f = expf(wff[idx]) * scij;
    float l = 0.5f * (expf(wll[idx]) * scij + expf(wll[ji]) * sc[ji]);
    eb = fmaf(b, b, eb); ef = fmaf(f, f, ef); el = fmaf(l, l, el);
  }
  wave_reduce3(eb, ef, el);
  __shared__ float red[3][4];
  int lane = threadIdx.x & 63, wv = threadIdx.x >> 6;
  if (lane == 0) { red[0][wv] = eb; red[1][wv] = ef; red[2][wv] = el; }
  __syncthreads();
  if (threadIdx.x == 0) {
    part[blockIdx.x]       = red[0][0] + red[0][1] + red[0][2] + red[0][3];
    part[64 + blockIdx.x]  = red[1][0] + red[1][1] + red[1][2] + red[1][3];
    part[128 + blockIdx.x] = red[2][0] + red[2][1] + red[2][2] + red[2][3];
  }
}

// ---------------------------------------------------------------------------
// Kernel B: ONE node per wave (r2 proved per-wave issue cadence ~3.4 cyc/instr
// independent of ILP -> minimize instructions/step/wave).
// Interleaved ring: slot s = NR*lane + r. Rotation by 1 = register rename
// (folded into scatter fma) + one DPP wave_rol for the top reg.
// Weights PRE-SCALED by dk*g_{l,f,b} so harvests are t1/t2/t3 directly.
// Harvest via ds_bpermute (VGPR result); dyn constants pinned in VGPRs so
// every dyn op has at most one SGPR operand (no materialization movs).
// ---------------------------------------------------------------------------
__global__ __launch_bounds__(64) void sim_kernel(
    const float* __restrict__ external, const float* __restrict__ hx,
    const float* __restrict__ hE, const float* __restrict__ sc,
    const float* __restrict__ dist, const float* __restrict__ wbb,
    const float* __restrict__ wff, const float* __restrict__ wll,
    const float* __restrict__ theta, const float* __restrict__ part,
    float* __restrict__ vsnap) {
  const int node = blockIdx.x;
  const int lane = threadIdx.x;

  __shared__ float Wall[3 * WSTR];   // Wl | Wf | Wb delay bins (pre-scaled)
  __shared__ float hE_lds[DMAX];
  __shared__ float u_lds[STEPS * TRS];

  // --- global norm sums from ssq partials (one DPP reduce) ---
  float sb = part[lane], sf = part[64 + lane], sl = part[128 + lane];
  wave_reduce3(sb, sf, sl);
  const float inv_nb = 1.f / sqrtf(sb);
  const float inv_nf = 1.f / sqrtf(sf);
  const float inv_nl = 1.f / sqrtf(sl);

  // --- parameters ---
  const float VL = relu_(theta[0]), VI = relu_(theta[1]);
  const float VE = relu_(theta[2]), VNMDA = relu_(theta[3]);
  const float alpha_mg = relu_(theta[4]), VR = relu_(theta[5]);
  const float pi_sigma = relu_(theta[6]);
  const float gLp = relu_(theta[7]), Cc = relu_(theta[8]), kappa = relu_(theta[9]);
  const float g_gE = relu_(theta[10]), g_gE_sc = relu_(theta[11]);
  const float g_gI = relu_(theta[12]), g_gI_sc = relu_(theta[13]);
  const float g_gN = relu_(theta[14]), g_gN_sc = relu_(theta[15]);
  const float g_k = relu_(theta[16]);
  const float mu = 0.1f + relu_(theta[20]);
  const float uk = relu_(theta[21]) * theta[23];
  const float g_l = relu_(theta[24]), g_f = relu_(theta[25]), g_b = relu_(theta[26]);
  const float DTC = DT / Cc;
  const float dk = DT * kappa;
  const float nps = -pi_sigma, psVR = pi_sigma * VR;
  const float nam = -alpha_mg;

  const float dk1  = 1.f - dk;
  const float cA   = dk * g_l;     // folded into Wl bins
  const float cF   = dk * g_f;     // folded into Wf bins
  const float cB   = dk * g_b;     // folded into Wb bins
  const float cE0s = dk * g_gE;
  const float cE1e = dk * g_gE_sc;
  const float cE2e = dk * g_k;
  const float cI0  = dk * g_gI;
  const float cI1  = dk * g_gI_sc;
  const float cN0s = dk * g_gN;
  const float cN1  = dk * g_gN_sc;
  const float cN2  = dk * g_gN;
  const float gLVL = gLp * VL;

  // --- stage LDS: zero W bins, history, pre-scaled external drive ---
  for (int k = lane; k < 3 * WSTR; k += 64) Wall[k] = 0.f;
  for (int d = lane; d < DMAX; d += 64) hE_lds[d] = hE[node * DMAX + d];
  const float ukdk = dk * uk;
  for (int t = lane; t < STEPS * TRS; t += 64)
    u_lds[t] = ukdk * external[node * STEPS * TRS + t];

  // --- bin weights by delay (LDS float atomics), scaled; row sums (scaled);
  //     max delay ---
  const float scl = inv_nl * cA, scf = inv_nf * cF, scb = inv_nb * cB;
  float rl = 0.f, rf = 0.f, rb = 0.f;
  int mymax = 0;
#pragma unroll
  for (int kj = 0; kj < JPL; ++kj) {
    int j = lane + kj * 64;
    if (j < NODE) {
      int ij = node * NODE + j;
      int ji = j * NODE + node;
      float scij = sc[ij];
      float vb = expf(wbb[ij]) * scij * scb;
      float vf = expf(wff[ij]) * scij * scf;
      float vl = 0.5f * (expf(wll[ij]) * scij + expf(wll[ji]) * sc[ji]) * scl;
      int dd = (int)(dist[ij] / mu);
      dd = min(max(dd, 0), DMAX - 1);
      atomicAdd(&Wall[dd], vl);
      atomicAdd(&Wall[WSTR + dd], vf);
      atomicAdd(&Wall[2 * WSTR + dd], vb);
      rl += vl; rf += vf; rb += vb;
      mymax = max(mymax, dd);
    }
  }
  wave_reduce3(rl, rf, rb);
  const int maxd = wave_max_int(mymax);

  // sP coefficients with (scaled) row-sum terms folded:
  // original cE0s2 = cE0s - cA*rs_l  and rl here is already cA*rs_l.
  const float cE0s2 = cE0s - rl;
  const float cN0s2 = cN0s - rl;
  const float cE1s = -rb;          // was -cB*rs_b
  const float cE2s = -rf;          // was -cF*rs_f

  // --- initial state (replicated across lanes) ---
  const int hb = node * POP * 4;
  float V0 = hx[hb + 0], V1 = hx[hb + 4], V2 = hx[hb + 8];
  float E0 = hx[hb + 1], E1 = hx[hb + 5], E2 = hx[hb + 9];
  float I0 = hx[hb + 2], I1 = hx[hb + 6], I2 = hx[hb + 10];
  float N0 = hx[hb + 3], N1 = hx[hb + 7], N2 = hx[hb + 11];

  // --- packed-transcendental lane constants (lanes 0-5 meaningful):
  // lane 0..2: sigmoid args for V0,V1,V2 ; lane 3..5: mN exp args
  const float L2E = 1.44269504088896f;
  const bool loS = (lane < 3);
  const float caL = loS ? nps * L2E : nam * L2E;
  const float cbL = loS ? psVR * L2E : 0.f;
  const float cdL = loS ? 1.f : 0.2f;
  const bool selB = (lane == 1) || (lane == 4);
  const bool selC = (lane == 2) || (lane == 5);
  const bool is63 = (lane == 63);

  // --- VGPR-pinned dyn constants: these pair with SGPR broadcast values
  // (sE/sI/sP from readlane) -> keeping them in VGPRs makes every op a legal
  // single-SGPR instruction (no per-use v_mov materialization).
  float vE0s2 = cE0s2; PIN_V(vE0s2);
  float vN0s2 = cN0s2; PIN_V(vN0s2);
  float vE1e  = cE1e;  PIN_V(vE1e);
  float vE1s  = cE1s;  PIN_V(vE1s);
  float vE2e  = cE2e;  PIN_V(vE2e);
  float vE2s  = cE2s;  PIN_V(vE2s);
  float vI0   = cI0;   PIN_V(vI0);
  float vI1   = cI1;   PIN_V(vI1);
  float vN1   = cN1;   PIN_V(vN1);
  float vN2   = cN2;   PIN_V(vN2);
  float vngLVL = -gLVL; PIN_V(vngLVL);

  auto core = [&](auto nrtag) {
    constexpr int NR = decltype(nrtag)::value;
    // Ring capacity 64*NR slots (slot s = NR*lane + r).

    // --- static per-lane weights: reg r lane L = Wbins[NR*L + r] ---
    float Wl[NR], Wf[NR], Wb[NR];
#pragma unroll
    for (int r = 0; r < NR; ++r) {
      int s = NR * lane + r;
      Wl[r] = Wall[s];
      Wf[r] = Wall[WSTR + s];
      Wb[r] = Wall[2 * WSTR + s];
    }

    // --- prologue: P[slot s] = sum_{d >= s} W[d] * hE[d - s].
    float Pl[NR], Pf[NR], Pb[NR], hbuf[NR];
#pragma unroll
    for (int r = 0; r < NR; ++r) { Pl[r] = 0.f; Pf[r] = 0.f; Pb[r] = 0.f; hbuf[r] = 0.f; }
    for (int d = 0; d <= maxd; ++d) {
      float wl_ = Wall[d], wf_ = Wall[WSTR + d], wb_ = Wall[2 * WSTR + d];
#pragma unroll
      for (int r = NR - 1; r > 0; --r) hbuf[r] = hbuf[r - 1];
      int idx = d - NR * lane;
      bool ok = idx >= 0;
      float h = hE_lds[ok ? idx : 0];
      hbuf[0] = ok ? h : 0.f;
#pragma unroll
      for (int r = 0; r < NR; ++r) {
        Pl[r] = fmaf(wl_, hbuf[r], Pl[r]);
        Pf[r] = fmaf(wf_, hbuf[r], Pf[r]);
        Pb[r] = fmaf(wb_, hbuf[r], Pb[r]);
      }
    }

    // rotate-by-1 (rename + 1 dpp) fused with scatter: after harvest of slot 0,
    // new P[r] = old P[r+1] + W[r]*sP ; new P[NR-1] = (shift-in) + W[NR-1]*sP
    auto rotscat = [&](float* P, const float* W, float sPv) {
      float nl = is63 ? 0.f : wrol1(P[0]);
#pragma unroll
      for (int r = 0; r < NR - 1; ++r) P[r] = fmaf(W[r], sPv, P[r + 1]);
      P[NR - 1] = fmaf(W[NR - 1], sPv, nl);
    };

    for (int tr = 0; tr < TRS; ++tr) {
      float u_tr = (lane < STEPS) ? u_lds[lane * TRS + tr] : 0.f;
#pragma unroll
      for (int st = 0; st < STEPS; ++st) {
        // 1) harvest (pre-scaled): t1/t2/t3 land in VGPRs on every lane
        float t1 = bperm0_(Pl[0]);
        float t2 = bperm0_(Pf[0]);
        float t3 = bperm0_(Pb[0]);

        // 2) packed sigmoid + mN: ONE v_exp + ONE v_rcp for all six values
        float Vs = selC ? V2 : (selB ? V1 : V0);
        float ex = __builtin_amdgcn_exp2f(fmaf(caL, Vs, cbL));
        float sg = rcp_(fmaf(cdL, ex, 1.f));
        float sE = rlane_(sg, 0), sI = rlane_(sg, 1), sP = rlane_(sg, 2);
        float m0 = rlane_(sg, 3), m1 = rlane_(sg, 4), m2 = rlane_(sg, 5);
        float U = rlane_(u_tr, st);            // SGPR; pairs with VGPR t1/t2

        // 3) dynamics (replicated; all ops <=1 SGPR operand)
        float T0 = t1 + U;
        float T2 = t2 + U;
        float nE0 = fmaf(dk1, E0, fmaf(vE0s2, sP, T0));
        float nN0 = fmaf(dk1, N0, fmaf(vN0s2, sP, t1));
        float nE1 = fmaf(dk1, E1, fmaf(vE1e, sE, fmaf(vE1s, sP, t3)));
        float nN1 = fmaf(dk1, N1, vN1 * sE);
        float nE2 = fmaf(dk1, E2, fmaf(vE2e, sE, fmaf(vE2s, sP, T2)));
        float nN2 = fmaf(dk1, N2, vN2 * sE);
        float pI = vI0 * sI;
        float nI0 = fmaf(dk1, I0, pI);
        float nI1 = fmaf(dk1, I1, vI1 * sI);
        float nI2 = fmaf(dk1, I2, pI);

        float Nm0 = N0 * m0, Nm1 = N1 * m1, Nm2 = N2 * m2;
        float R0 = fmaf(E0, VE, fmaf(Nm0, VNMDA, fmaf(I0, -VI, vngLVL)));
        float R1 = fmaf(E1, VE, fmaf(Nm1, VNMDA, fmaf(I1, -VI, vngLVL)));
        float R2 = fmaf(E2, VE, fmaf(Nm2, VNMDA, fmaf(I2, -VI, vngLVL)));
        float S0 = gLp + E0 + I0 + Nm0;
        float S1 = gLp + E1 + I1 + Nm1;
        float S2 = gLp + E2 + I2 + Nm2;
        V0 = fmaf(DTC, fmaf(-S0, V0, R0), V0);
        V1 = fmaf(DTC, fmaf(-S1, V1, R1), V1);
        V2 = fmaf(DTC, fmaf(-S2, V2, R2), V2);
        E0 = nE0; E1 = nE1; E2 = nE2;
        I0 = nI0; I1 = nI1; I2 = nI2;
        N0 = nN0; N1 = nN1; N2 = nN2;

        // 4) rotate + scatter (sP stays SGPR: fma(W_v, sP_s, P_v) is legal)
        rotscat(Pl, Wl, sP);
        rotscat(Pf, Wf, sP);
        rotscat(Pb, Wb, sP);
      }
      if (lane == 0) vsnap[tr * NODE + node] = V2;
    }
  };

  if (maxd <= 126) core(std::integral_constant<int, 2>{});
  else             core(std::integral_constant<int, 8>{});
}

// ---------------------------------------------------------------------------
// Kernel C: EEG readout, 4 waves split the n-dimension.
// ---------------------------------------------------------------------------
__global__ __launch_bounds__(256) void eeg_kernel(
    const float* __restrict__ lm, const float* __restrict__ vsnap,
    const float* __restrict__ theta, float* __restrict__ out) {
  int tr = blockIdx.x;
  __shared__ float cm[NODE];
  __shared__ float vs[NODE];
  __shared__ float partl[4][OUT];
  int tid = threadIdx.x;
  for (int n = tid; n < NODE; n += 256) {
    float s = 0.f;
    for (int o = 0; o < OUT; ++o) s += lm[o * NODE + n];
    cm[n] = s * (1.f / OUT);
    vs[n] = vsnap[tr * NODE + n];
  }
  __syncthreads();
  int o = tid & 63, w = tid >> 6;
  float acc = 0.f;
  for (int n = w * 100; n < w * 100 + 100; ++n)
    acc = fmaf(lm[o * NODE + n] - cm[n], vs[n], acc);
  partl[w][o] = acc;
  __syncthreads();
  if (tid < OUT) {
    float cy0 = theta[22], y0 = theta[19];
    out[tr * OUT + tid] =
        cy0 * (partl[0][tid] + partl[1][tid] + partl[2][tid] + partl[3][tid]) - y0;
  }
}

extern "C" void kernel_launch(void* const* d_in, const int* in_sizes, int n_in,
                              void* d_out, int out_size, void* d_ws, size_t ws_size,
                              hipStream_t stream) {
  const float* external = (const float*)d_in[0];
  const float* hx       = (const float*)d_in[1];
  const float* hE       = (const float*)d_in[2];
  const float* sc       = (const float*)d_in[3];
  const float* dist     = (const float*)d_in[4];
  const float* wbb      = (const float*)d_in[5];
  const float* wff      = (const float*)d_in[6];
  const float* wll      = (const float*)d_in[7];
  const float* lm       = (const float*)d_in[8];
  const float* theta    = (const float*)d_in[9];
  float* out = (float*)d_out;

  float* vsnap = (float*)d_ws;               // TRS*NODE
  float* part  = vsnap + TRS * NODE;         // 3*64 ssq partials

  ssq_kernel<<<64, 256, 0, stream>>>(wbb, wff, wll, sc, part);
  sim_kernel<<<NODE, 64, 0, stream>>>(external, hx, hE, sc, dist, wbb, wff, wll,
                                      theta, part, vsnap);
  eeg_kernel<<<TRS, 256, 0, stream>>>(lm, vsnap, theta, out);
}

// Round 4
// 186.793 us; speedup vs baseline: 1.3007x; 1.0439x over previous
//
#include <hip/hip_runtime.h>
#include <type_traits>

#define NODE 400
#define POP 3
#define TRS 40
#define STEPS 10
#define DMAX 500
#define OUT 64
#define DT 0.1f
#define JPL 7           // ceil(NODE/64) j-indices per lane
#define WSTR 512        // per-stream W bin stride (delta in [0,511])

__device__ __forceinline__ float relu_(float x) { return x > 0.f ? x : 0.f; }
__device__ __forceinline__ float rcp_(float x) { return __builtin_amdgcn_rcpf(x); }
__device__ __forceinline__ float rlane_(float v, int l) {
  return __builtin_bit_cast(float, __builtin_amdgcn_readlane(__builtin_bit_cast(int, v), l));
}
// broadcast lane 0 to all lanes, VGPR result (slow-path harvest)
__device__ __forceinline__ float bperm0_(float v) {
  return __builtin_bit_cast(float,
      __builtin_amdgcn_ds_bpermute(0, __builtin_bit_cast(int, v)));
}
// ds_swizzle BitMode: src_lane = ((lane & and) | or) ^ xor within each
// 32-lane group. OFF = (xor<<10)|(or<<5)|and. With and=0,xor=0: every lane
// reads lane 'or' of its OWN 32-group -> half-local broadcast.
template <int OFF>
__device__ __forceinline__ float swz_(float v) {
  return __builtin_bit_cast(float,
      __builtin_amdgcn_ds_swizzle(__builtin_bit_cast(int, v), OFF));
}
// pin a value into a VGPR
#define PIN_V(x) asm volatile("" : "+v"(x))

// ---- DPP helpers
template <int CTRL>
__device__ __forceinline__ float dpp_mov(float x) {
  int r = __builtin_amdgcn_update_dpp(0, __builtin_bit_cast(int, x), CTRL,
                                      0xf, 0xf, true);
  return __builtin_bit_cast(float, r);
}
template <int CTRL>
__device__ __forceinline__ int dpp_movi(int x) {
  return __builtin_amdgcn_update_dpp(0, x, CTRL, 0xf, 0xf, true);
}
// wave rotate: dst[L] = src[(L+1) & 63]  (wave_rol:1 = 0x134, verified r1-r3)
__device__ __forceinline__ float wrol1(float x) { return dpp_mov<0x134>(x); }

__device__ __forceinline__ void wave_reduce3(float& a, float& b, float& c) {
  a += dpp_mov<0x111>(a); b += dpp_mov<0x111>(b); c += dpp_mov<0x111>(c);
  a += dpp_mov<0x112>(a); b += dpp_mov<0x112>(b); c += dpp_mov<0x112>(c);
  a += dpp_mov<0x114>(a); b += dpp_mov<0x114>(b); c += dpp_mov<0x114>(c);
  a += dpp_mov<0x118>(a); b += dpp_mov<0x118>(b); c += dpp_mov<0x118>(c);
  a += dpp_mov<0x142>(a); b += dpp_mov<0x142>(b); c += dpp_mov<0x142>(c);
  a += dpp_mov<0x143>(a); b += dpp_mov<0x143>(b); c += dpp_mov<0x143>(c);
  a = rlane_(a, 63); b = rlane_(b, 63); c = rlane_(c, 63);
}

__device__ __forceinline__ int wave_max_int(int x) {
  x = max(x, dpp_movi<0x111>(x));
  x = max(x, dpp_movi<0x112>(x));
  x = max(x, dpp_movi<0x114>(x));
  x = max(x, dpp_movi<0x118>(x));
  x = max(x, dpp_movi<0x142>(x));
  x = max(x, dpp_movi<0x143>(x));
  return __builtin_amdgcn_readlane(x, 63);
}

// ---------------------------------------------------------------------------
// Kernel A: Frobenius sum-of-squares partials (64 blocks, no atomics).
// ---------------------------------------------------------------------------
__global__ __launch_bounds__(256) void ssq_kernel(
    const float* __restrict__ wbb, const float* __restrict__ wff,
    const float* __restrict__ wll, const float* __restrict__ sc,
    float* __restrict__ part) {
  float eb = 0.f, ef = 0.f, el = 0.f;
  for (int idx = blockIdx.x * 256 + threadIdx.x; idx < NODE * NODE;
       idx += 64 * 256) {
    int i = idx / NODE, j = idx - i * NODE;
    int ji = j * NODE + i;
    float scij = sc[idx];
    float b = expf(wbb[idx]) * scij;
    float f = expf(wff[idx]) * scij;
    float l = 0.5f * (expf(wll[idx]) * scij + expf(wll[ji]) * sc[ji]);
    eb = fmaf(b, b, eb); ef = fmaf(f, f, ef); el = fmaf(l, l, el);
  }
  wave_reduce3(eb, ef, el);
  __shared__ float red[3][4];
  int lane = threadIdx.x & 63, wv = threadIdx.x >> 6;
  if (lane == 0) { red[0][wv] = eb; red[1][wv] = ef; red[2][wv] = el; }
  __syncthreads();
  if (threadIdx.x == 0) {
    part[blockIdx.x]       = red[0][0] + red[0][1] + red[0][2] + red[0][3];
    part[64 + blockIdx.x]  = red[1][0] + red[1][1] + red[1][2] + red[1][3];
    part[128 + blockIdx.x] = red[2][0] + red[2][1] + red[2][2] + red[2][3];
  }
}

// ---------------------------------------------------------------------------
// Kernel B: TWO nodes per block. Setup: wave w bins node w. Fast path
// (maxd<=126): wave 0 alone simulates BOTH nodes with 32-lane halves —
// lanes 0-31 = node A (replicated state), 32-63 = node B. The ~47-op scalar
// dynamics stream is SHARED across both nodes (per-lane VGPR coefficients).
// Ring per half: 32 lanes x NR=4 regs = 128 slots (slot = 4*hlane + r).
// Cross-half distribution via ds_swizzle half-broadcast (batched, 1 wait).
// Slow path (maxd>126): each wave runs the proven r3 full-wave NR=8 core.
// ---------------------------------------------------------------------------
__global__ __launch_bounds__(128) void sim_kernel(
    const float* __restrict__ external, const float* __restrict__ hx,
    const float* __restrict__ hE, const float* __restrict__ sc,
    const float* __restrict__ dist, const float* __restrict__ wbb,
    const float* __restrict__ wff, const float* __restrict__ wll,
    const float* __restrict__ theta, const float* __restrict__ part,
    float* __restrict__ vsnap) {
  const int wv = threadIdx.x >> 6;
  const int lane = threadIdx.x & 63;
  const int node = blockIdx.x * 2 + wv;   // this wave's setup node

  __shared__ float Wall[2][3 * WSTR];   // per node: Wl | Wf | Wb (pre-scaled)
  __shared__ float hE_lds[2][DMAX];
  __shared__ float u_lds[2][STEPS * TRS];
  __shared__ float sc_c[2][3];          // rl, rf, rb (scaled row sums)
  __shared__ int   sc_md[2];            // per-node maxd

  // --- global norm sums from ssq partials (one DPP reduce) ---
  float sb = part[lane], sf = part[64 + lane], sl = part[128 + lane];
  wave_reduce3(sb, sf, sl);
  const float inv_nb = 1.f / sqrtf(sb);
  const float inv_nf = 1.f / sqrtf(sf);
  const float inv_nl = 1.f / sqrtf(sl);

  // --- parameters ---
  const float VL = relu_(theta[0]), VI = relu_(theta[1]);
  const float VE = relu_(theta[2]), VNMDA = relu_(theta[3]);
  const float alpha_mg = relu_(theta[4]), VR = relu_(theta[5]);
  const float pi_sigma = relu_(theta[6]);
  const float gLp = relu_(theta[7]), Cc = relu_(theta[8]), kappa = relu_(theta[9]);
  const float g_gE = relu_(theta[10]), g_gE_sc = relu_(theta[11]);
  const float g_gI = relu_(theta[12]), g_gI_sc = relu_(theta[13]);
  const float g_gN = relu_(theta[14]), g_gN_sc = relu_(theta[15]);
  const float g_k = relu_(theta[16]);
  const float mu = 0.1f + relu_(theta[20]);
  const float uk = relu_(theta[21]) * theta[23];
  const float g_l = relu_(theta[24]), g_f = relu_(theta[25]), g_b = relu_(theta[26]);
  const float DTC = DT / Cc;
  const float dk = DT * kappa;
  const float nps = -pi_sigma, psVR = pi_sigma * VR;
  const float nam = -alpha_mg;

  const float dk1  = 1.f - dk;
  const float cA   = dk * g_l;     // folded into Wl bins
  const float cF   = dk * g_f;     // folded into Wf bins
  const float cB   = dk * g_b;     // folded into Wb bins
  const float cE0s = dk * g_gE;
  const float cE1e = dk * g_gE_sc;
  const float cE2e = dk * g_k;
  const float cI0  = dk * g_gI;
  const float cI1  = dk * g_gI_sc;
  const float cN0s = dk * g_gN;
  const float cN1  = dk * g_gN_sc;
  const float cN2  = dk * g_gN;
  const float gLVL = gLp * VL;
  const float L2E = 1.44269504088896f;

  // --- stage LDS (wave w handles node w's slabs) ---
  for (int k = lane; k < 3 * WSTR; k += 64) Wall[wv][k] = 0.f;
  for (int d = lane; d < DMAX; d += 64) hE_lds[wv][d] = hE[node * DMAX + d];
  const float ukdk = dk * uk;
  for (int t = lane; t < STEPS * TRS; t += 64)
    u_lds[wv][t] = ukdk * external[node * STEPS * TRS + t];

  // --- bin weights by delay (pre-scaled), row sums, max delay ---
  const float scl = inv_nl * cA, scf = inv_nf * cF, scb = inv_nb * cB;
  float rl = 0.f, rf = 0.f, rb = 0.f;
  int mymax = 0;
#pragma unroll
  for (int kj = 0; kj < JPL; ++kj) {
    int j = lane + kj * 64;
    if (j < NODE) {
      int ij = node * NODE + j;
      int ji = j * NODE + node;
      float scij = sc[ij];
      float vb = expf(wbb[ij]) * scij * scb;
      float vf = expf(wff[ij]) * scij * scf;
      float vl = 0.5f * (expf(wll[ij]) * scij + expf(wll[ji]) * sc[ji]) * scl;
      int dd = (int)(dist[ij] / mu);
      dd = min(max(dd, 0), DMAX - 1);
      atomicAdd(&Wall[wv][dd], vl);
      atomicAdd(&Wall[wv][WSTR + dd], vf);
      atomicAdd(&Wall[wv][2 * WSTR + dd], vb);
      rl += vl; rf += vf; rb += vb;
      mymax = max(mymax, dd);
    }
  }
  wave_reduce3(rl, rf, rb);
  const int maxd_w = wave_max_int(mymax);
  if (lane == 0) {
    sc_c[wv][0] = rl; sc_c[wv][1] = rf; sc_c[wv][2] = rb;
    sc_md[wv] = maxd_w;
  }
  __syncthreads();
  const int maxd = max(sc_md[0], sc_md[1]);

  if (maxd <= 126) {
    // ================= FAST PATH: wave 0 only, 32-lane halves ==============
    if (wv != 0) return;
    const int h = lane >> 5, hlane = lane & 31;
    const int nodeF = blockIdx.x * 2 + h;

    // per-lane (per-node) coefficients
    const float rlh = sc_c[h][0], rfh = sc_c[h][1], rbh = sc_c[h][2];
    const float cE0s2 = cE0s - rlh;    // VGPR by construction
    const float cN0s2 = cN0s - rlh;
    const float cE1s = -rbh;
    const float cE2s = -rfh;
    float vngLVL = -gLVL; PIN_V(vngLVL);

    // initial state (replicated within half)
    const int hb = nodeF * POP * 4;
    float V0 = hx[hb + 0], V1 = hx[hb + 4], V2 = hx[hb + 8];
    float E0 = hx[hb + 1], E1 = hx[hb + 5], E2 = hx[hb + 9];
    float I0 = hx[hb + 2], I1 = hx[hb + 6], I2 = hx[hb + 10];
    float N0 = hx[hb + 3], N1 = hx[hb + 7], N2 = hx[hb + 11];

    // packed-trans lane constants: hlane 0-2 sigmoid(V0,V1,V2), 3-5 mN
    const bool loS = hlane < 3;
    const float caL = loS ? nps * L2E : nam * L2E;
    const float cbL = loS ? psVR * L2E : 0.f;
    const float cdL = loS ? 1.f : 0.2f;
    const bool selB = (hlane == 1) || (hlane == 4);
    const bool selC = (hlane == 2) || (hlane == 5);
    const bool htop = (hlane == 31);

    // static per-lane weights: slot s = 4*hlane + r
    constexpr int NR = 4;
    float Wl[NR], Wf[NR], Wb[NR];
#pragma unroll
    for (int r = 0; r < NR; ++r) {
      int s = NR * hlane + r;
      Wl[r] = Wall[h][s];
      Wf[r] = Wall[h][WSTR + s];
      Wb[r] = Wall[h][2 * WSTR + s];
    }

    // prologue: P[slot s] = sum_{d>=s} W[d]*hE[d-s]
    float Pl[NR], Pf[NR], Pb[NR], hbuf[NR];
#pragma unroll
    for (int r = 0; r < NR; ++r) { Pl[r] = 0.f; Pf[r] = 0.f; Pb[r] = 0.f; hbuf[r] = 0.f; }
    for (int d = 0; d <= maxd; ++d) {
      float wl_ = Wall[h][d], wf_ = Wall[h][WSTR + d], wb_ = Wall[h][2 * WSTR + d];
#pragma unroll
      for (int r = NR - 1; r > 0; --r) hbuf[r] = hbuf[r - 1];
      int idx = d - NR * hlane;
      bool ok = idx >= 0;
      float hv = hE_lds[h][ok ? idx : 0];
      hbuf[0] = ok ? hv : 0.f;
#pragma unroll
      for (int r = 0; r < NR; ++r) {
        Pl[r] = fmaf(wl_, hbuf[r], Pl[r]);
        Pf[r] = fmaf(wf_, hbuf[r], Pf[r]);
        Pb[r] = fmaf(wb_, hbuf[r], Pb[r]);
      }
    }

    const float* uh = &u_lds[h][0];
    for (int tr = 0; tr < TRS; ++tr) {
#pragma unroll
      for (int st = 0; st < STEPS; ++st) {
        // 1) packed sigmoid + mN (one exp2 + one rcp for both nodes' 6 vals)
        float Vs = selC ? V2 : (selB ? V1 : V0);
        float ex = __builtin_amdgcn_exp2f(fmaf(caL, Vs, cbL));
        float sg = rcp_(fmaf(cdL, ex, 1.f));

        // 2) batched half-broadcast distribution (one lgkm wait for all)
        float sE = swz_<(0 << 5)>(sg);
        float sI = swz_<(1 << 5)>(sg);
        float sP = swz_<(2 << 5)>(sg);
        float m0 = swz_<(3 << 5)>(sg);
        float m1 = swz_<(4 << 5)>(sg);
        float m2 = swz_<(5 << 5)>(sg);
        float t1 = swz_<(0 << 5)>(Pl[0]);   // harvest slot0 of own half
        float t2 = swz_<(0 << 5)>(Pf[0]);
        float t3 = swz_<(0 << 5)>(Pb[0]);
        float U  = uh[st * TRS + tr];       // uniform-per-half LDS read

        // 3) ring rotate helpers (read OLD P[0] before scatter overwrites)
        float nll = htop ? 0.f : wrol1(Pl[0]);
        float nlf = htop ? 0.f : wrol1(Pf[0]);
        float nlb = htop ? 0.f : wrol1(Pb[0]);

        // 4) dynamics — shared instruction stream, per-lane node values
        float T0 = t1 + U;
        float T2 = t2 + U;
        float nE0 = fmaf(dk1, E0, fmaf(cE0s2, sP, T0));
        float nN0 = fmaf(dk1, N0, fmaf(cN0s2, sP, t1));
        float nE1 = fmaf(dk1, E1, fmaf(cE1e, sE, fmaf(cE1s, sP, t3)));
        float nN1 = fmaf(dk1, N1, cN1 * sE);
        float nE2 = fmaf(dk1, E2, fmaf(cE2e, sE, fmaf(cE2s, sP, T2)));
        float nN2 = fmaf(dk1, N2, cN2 * sE);
        float pI = cI0 * sI;
        float nI0 = fmaf(dk1, I0, pI);
        float nI1 = fmaf(dk1, I1, cI1 * sI);
        float nI2 = fmaf(dk1, I2, pI);

        float Nm0 = N0 * m0, Nm1 = N1 * m1, Nm2 = N2 * m2;
        float R0 = fmaf(E0, VE, fmaf(Nm0, VNMDA, fmaf(I0, -VI, vngLVL)));
        float R1 = fmaf(E1, VE, fmaf(Nm1, VNMDA, fmaf(I1, -VI, vngLVL)));
        float R2 = fmaf(E2, VE, fmaf(Nm2, VNMDA, fmaf(I2, -VI, vngLVL)));
        float S0 = gLp + E0 + I0 + Nm0;
        float S1 = gLp + E1 + I1 + Nm1;
        float S2 = gLp + E2 + I2 + Nm2;
        V0 = fmaf(DTC, fmaf(-S0, V0, R0), V0);
        V1 = fmaf(DTC, fmaf(-S1, V1, R1), V1);
        V2 = fmaf(DTC, fmaf(-S2, V2, R2), V2);
        E0 = nE0; E1 = nE1; E2 = nE2;
        I0 = nI0; I1 = nI1; I2 = nI2;
        N0 = nN0; N1 = nN1; N2 = nN2;

        // 5) rotate(rename)+scatter: new P[r] = old P[r+1] + W[r]*sP
        Pl[0] = fmaf(Wl[0], sP, Pl[1]);
        Pl[1] = fmaf(Wl[1], sP, Pl[2]);
        Pl[2] = fmaf(Wl[2], sP, Pl[3]);
        Pl[3] = fmaf(Wl[3], sP, nll);
        Pf[0] = fmaf(Wf[0], sP, Pf[1]);
        Pf[1] = fmaf(Wf[1], sP, Pf[2]);
        Pf[2] = fmaf(Wf[2], sP, Pf[3]);
        Pf[3] = fmaf(Wf[3], sP, nlf);
        Pb[0] = fmaf(Wb[0], sP, Pb[1]);
        Pb[1] = fmaf(Wb[1], sP, Pb[2]);
        Pb[2] = fmaf(Wb[2], sP, Pb[3]);
        Pb[3] = fmaf(Wb[3], sP, nlb);
      }
      if (hlane == 0) vsnap[tr * NODE + nodeF] = V2;
    }
    return;
  }

  // ================= SLOW PATH (maxd>126): r3 core, wave w = node w ========
  {
    const float cE0s2 = cE0s - rl;
    const float cN0s2 = cN0s - rl;
    const float cE1s = -rb;
    const float cE2s = -rf;

    const int hb = node * POP * 4;
    float V0 = hx[hb + 0], V1 = hx[hb + 4], V2 = hx[hb + 8];
    float E0 = hx[hb + 1], E1 = hx[hb + 5], E2 = hx[hb + 9];
    float I0 = hx[hb + 2], I1 = hx[hb + 6], I2 = hx[hb + 10];
    float N0 = hx[hb + 3], N1 = hx[hb + 7], N2 = hx[hb + 11];

    const bool loS = (lane < 3);
    const float caL = loS ? nps * L2E : nam * L2E;
    const float cbL = loS ? psVR * L2E : 0.f;
    const float cdL = loS ? 1.f : 0.2f;
    const bool selB = (lane == 1) || (lane == 4);
    const bool selC = (lane == 2) || (lane == 5);
    const bool is63 = (lane == 63);

    float vE0s2 = cE0s2; PIN_V(vE0s2);
    float vN0s2 = cN0s2; PIN_V(vN0s2);
    float vE1e  = cE1e;  PIN_V(vE1e);
    float vE1s  = cE1s;  PIN_V(vE1s);
    float vE2e  = cE2e;  PIN_V(vE2e);
    float vE2s  = cE2s;  PIN_V(vE2s);
    float vI0   = cI0;   PIN_V(vI0);
    float vI1   = cI1;   PIN_V(vI1);
    float vN1   = cN1;   PIN_V(vN1);
    float vN2   = cN2;   PIN_V(vN2);
    float vngLVL = -gLVL; PIN_V(vngLVL);

    constexpr int NR = 8;
    float Wl[NR], Wf[NR], Wb[NR];
#pragma unroll
    for (int r = 0; r < NR; ++r) {
      int s = NR * lane + r;
      Wl[r] = Wall[wv][s];
      Wf[r] = Wall[wv][WSTR + s];
      Wb[r] = Wall[wv][2 * WSTR + s];
    }

    float Pl[NR], Pf[NR], Pb[NR], hbuf[NR];
#pragma unroll
    for (int r = 0; r < NR; ++r) { Pl[r] = 0.f; Pf[r] = 0.f; Pb[r] = 0.f; hbuf[r] = 0.f; }
    for (int d = 0; d <= maxd; ++d) {
      float wl_ = Wall[wv][d], wf_ = Wall[wv][WSTR + d], wb_ = Wall[wv][2 * WSTR + d];
#pragma unroll
      for (int r = NR - 1; r > 0; --r) hbuf[r] = hbuf[r - 1];
      int idx = d - NR * lane;
      bool ok = idx >= 0;
      float hv = hE_lds[wv][ok ? idx : 0];
      hbuf[0] = ok ? hv : 0.f;
#pragma unroll
      for (int r = 0; r < NR; ++r) {
        Pl[r] = fmaf(wl_, hbuf[r], Pl[r]);
        Pf[r] = fmaf(wf_, hbuf[r], Pf[r]);
        Pb[r] = fmaf(wb_, hbuf[r], Pb[r]);
      }
    }

    auto rotscat = [&](float* P, const float* W, float sPv) {
      float nl = is63 ? 0.f : wrol1(P[0]);
#pragma unroll
      for (int r = 0; r < NR - 1; ++r) P[r] = fmaf(W[r], sPv, P[r + 1]);
      P[NR - 1] = fmaf(W[NR - 1], sPv, nl);
    };

    for (int tr = 0; tr < TRS; ++tr) {
      float u_tr = (lane < STEPS) ? u_lds[wv][lane * TRS + tr] : 0.f;
#pragma unroll
      for (int st = 0; st < STEPS; ++st) {
        float t1 = bperm0_(Pl[0]);
        float t2 = bperm0_(Pf[0]);
        float t3 = bperm0_(Pb[0]);

        float Vs = selC ? V2 : (selB ? V1 : V0);
        float ex = __builtin_amdgcn_exp2f(fmaf(caL, Vs, cbL));
        float sg = rcp_(fmaf(cdL, ex, 1.f));
        float sE = rlane_(sg, 0), sI = rlane_(sg, 1), sP = rlane_(sg, 2);
        float m0 = rlane_(sg, 3), m1 = rlane_(sg, 4), m2 = rlane_(sg, 5);
        float U = rlane_(u_tr, st);

        float T0 = t1 + U;
        float T2 = t2 + U;
        float nE0 = fmaf(dk1, E0, fmaf(vE0s2, sP, T0));
        float nN0 = fmaf(dk1, N0, fmaf(vN0s2, sP, t1));
        float nE1 = fmaf(dk1, E1, fmaf(vE1e, sE, fmaf(vE1s, sP, t3)));
        float nN1 = fmaf(dk1, N1, vN1 * sE);
        float nE2 = fmaf(dk1, E2, fmaf(vE2e, sE, fmaf(vE2s, sP, T2)));
        float nN2 = fmaf(dk1, N2, vN2 * sE);
        float pI = vI0 * sI;
        float nI0 = fmaf(dk1, I0, pI);
        float nI1 = fmaf(dk1, I1, vI1 * sI);
        float nI2 = fmaf(dk1, I2, pI);

        float Nm0 = N0 * m0, Nm1 = N1 * m1, Nm2 = N2 * m2;
        float R0 = fmaf(E0, VE, fmaf(Nm0, VNMDA, fmaf(I0, -VI, vngLVL)));
        float R1 = fmaf(E1, VE, fmaf(Nm1, VNMDA, fmaf(I1, -VI, vngLVL)));
        float R2 = fmaf(E2, VE, fmaf(Nm2, VNMDA, fmaf(I2, -VI, vngLVL)));
        float S0 = gLp + E0 + I0 + Nm0;
        float S1 = gLp + E1 + I1 + Nm1;
        float S2 = gLp + E2 + I2 + Nm2;
        V0 = fmaf(DTC, fmaf(-S0, V0, R0), V0);
        V1 = fmaf(DTC, fmaf(-S1, V1, R1), V1);
        V2 = fmaf(DTC, fmaf(-S2, V2, R2), V2);
        E0 = nE0; E1 = nE1; E2 = nE2;
        I0 = nI0; I1 = nI1; I2 = nI2;
        N0 = nN0; N1 = nN1; N2 = nN2;

        rotscat(Pl, Wl, sP);
        rotscat(Pf, Wf, sP);
        rotscat(Pb, Wb, sP);
      }
      if (lane == 0) vsnap[tr * NODE + node] = V2;
    }
  }
}

// ---------------------------------------------------------------------------
// Kernel C: EEG readout, 4 waves split the n-dimension.
// ---------------------------------------------------------------------------
__global__ __launch_bounds__(256) void eeg_kernel(
    const float* __restrict__ lm, const float* __restrict__ vsnap,
    const float* __restrict__ theta, float* __restrict__ out) {
  int tr = blockIdx.x;
  __shared__ float cm[NODE];
  __shared__ float vs[NODE];
  __shared__ float partl[4][OUT];
  int tid = threadIdx.x;
  for (int n = tid; n < NODE; n += 256) {
    float s = 0.f;
    for (int o = 0; o < OUT; ++o) s += lm[o * NODE + n];
    cm[n] = s * (1.f / OUT);
    vs[n] = vsnap[tr * NODE + n];
  }
  __syncthreads();
  int o = tid & 63, w = tid >> 6;
  float acc = 0.f;
  for (int n = w * 100; n < w * 100 + 100; ++n)
    acc = fmaf(lm[o * NODE + n] - cm[n], vs[n], acc);
  partl[w][o] = acc;
  __syncthreads();
  if (tid < OUT) {
    float cy0 = theta[22], y0 = theta[19];
    out[tr * OUT + tid] =
        cy0 * (partl[0][tid] + partl[1][tid] + partl[2][tid] + partl[3][tid]) - y0;
  }
}

extern "C" void kernel_launch(void* const* d_in, const int* in_sizes, int n_in,
                              void* d_out, int out_size, void* d_ws, size_t ws_size,
                              hipStream_t stream) {
  const float* external = (const float*)d_in[0];
  const float* hx       = (const float*)d_in[1];
  const float* hE       = (const float*)d_in[2];
  const float* sc       = (const float*)d_in[3];
  const float* dist     = (const float*)d_in[4];
  const float* wbb      = (const float*)d_in[5];
  const float* wff      = (const float*)d_in[6];
  const float* wll      = (const float*)d_in[7];
  const float* lm       = (const float*)d_in[8];
  const float* theta    = (const float*)d_in[9];
  float* out = (float*)d_out;

  float* vsnap = (float*)d_ws;               // TRS*NODE
  float* part  = vsnap + TRS * NODE;         // 3*64 ssq partials

  ssq_kernel<<<64, 256, 0, stream>>>(wbb, wff, wll, sc, part);
  sim_kernel<<<NODE / 2, 128, 0, stream>>>(external, hx, hE, sc, dist, wbb, wff,
                                           wll, theta, part, vsnap);
  eeg_kernel<<<TRS, 256, 0, stream>>>(lm, vsnap, theta, out);
}

// Round 5
// 173.800 us; speedup vs baseline: 1.3979x; 1.0748x over previous
//
#include <hip/hip_runtime.h>
#include <type_traits>

#define NODE 400
#define POP 3
#define TRS 40
#define STEPS 10
#define DMAX 500
#define OUT 64
#define DT 0.1f
#define JPL 7           // ceil(NODE/64) j-indices per lane
#define WSTR 512        // per-stream W bin stride (delta in [0,511])

__device__ __forceinline__ float relu_(float x) { return x > 0.f ? x : 0.f; }
__device__ __forceinline__ float rcp_(float x) { return __builtin_amdgcn_rcpf(x); }
__device__ __forceinline__ float rlane_(float v, int l) {
  return __builtin_bit_cast(float, __builtin_amdgcn_readlane(__builtin_bit_cast(int, v), l));
}
// broadcast lane 0 to all lanes, VGPR result (slow-path harvest)
__device__ __forceinline__ float bperm0_(float v) {
  return __builtin_bit_cast(float,
      __builtin_amdgcn_ds_bpermute(0, __builtin_bit_cast(int, v)));
}
// ds_swizzle BitMode: src_lane = ((lane & and) | or) ^ xor within each
// 32-lane group. OFF = (xor<<10)|(or<<5)|and. OFF=0 -> every lane reads
// lane 0 of its OWN 32-group (half-local broadcast).
template <int OFF>
__device__ __forceinline__ float swz_(float v) {
  return __builtin_bit_cast(float,
      __builtin_amdgcn_ds_swizzle(__builtin_bit_cast(int, v), OFF));
}
// pin a value into a VGPR
#define PIN_V(x) asm volatile("" : "+v"(x))

// ---- DPP helpers
template <int CTRL>
__device__ __forceinline__ float dpp_mov(float x) {
  int r = __builtin_amdgcn_update_dpp(0, __builtin_bit_cast(int, x), CTRL,
                                      0xf, 0xf, true);
  return __builtin_bit_cast(float, r);
}
template <int CTRL>
__device__ __forceinline__ int dpp_movi(int x) {
  return __builtin_amdgcn_update_dpp(0, x, CTRL, 0xf, 0xf, true);
}
// wave rotate: dst[L] = src[(L+1) & 63]  (wave_rol:1 = 0x134, verified r1-r4)
__device__ __forceinline__ float wrol1(float x) { return dpp_mov<0x134>(x); }

__device__ __forceinline__ void wave_reduce3(float& a, float& b, float& c) {
  a += dpp_mov<0x111>(a); b += dpp_mov<0x111>(b); c += dpp_mov<0x111>(c);
  a += dpp_mov<0x112>(a); b += dpp_mov<0x112>(b); c += dpp_mov<0x112>(c);
  a += dpp_mov<0x114>(a); b += dpp_mov<0x114>(b); c += dpp_mov<0x114>(c);
  a += dpp_mov<0x118>(a); b += dpp_mov<0x118>(b); c += dpp_mov<0x118>(c);
  a += dpp_mov<0x142>(a); b += dpp_mov<0x142>(b); c += dpp_mov<0x142>(c);
  a += dpp_mov<0x143>(a); b += dpp_mov<0x143>(b); c += dpp_mov<0x143>(c);
  a = rlane_(a, 63); b = rlane_(b, 63); c = rlane_(c, 63);
}

__device__ __forceinline__ float wave_reduce1(float a) {
  a += dpp_mov<0x111>(a); a += dpp_mov<0x112>(a); a += dpp_mov<0x114>(a);
  a += dpp_mov<0x118>(a); a += dpp_mov<0x142>(a); a += dpp_mov<0x143>(a);
  return rlane_(a, 63);
}

__device__ __forceinline__ int wave_max_int(int x) {
  x = max(x, dpp_movi<0x111>(x));
  x = max(x, dpp_movi<0x112>(x));
  x = max(x, dpp_movi<0x114>(x));
  x = max(x, dpp_movi<0x118>(x));
  x = max(x, dpp_movi<0x142>(x));
  x = max(x, dpp_movi<0x143>(x));
  return __builtin_amdgcn_readlane(x, 63);
}

// ---------------------------------------------------------------------------
// Kernel A: Frobenius sum-of-squares partials (64 blocks, no atomics).
// ---------------------------------------------------------------------------
__global__ __launch_bounds__(256) void ssq_kernel(
    const float* __restrict__ wbb, const float* __restrict__ wff,
    const float* __restrict__ wll, const float* __restrict__ sc,
    float* __restrict__ part) {
  float eb = 0.f, ef = 0.f, el = 0.f;
  for (int idx = blockIdx.x * 256 + threadIdx.x; idx < NODE * NODE;
       idx += 64 * 256) {
    int i = idx / NODE, j = idx - i * NODE;
    int ji = j * NODE + i;
    float scij = sc[idx];
    float b = expf(wbb[idx]) * scij;
    float f = expf(wff[idx]) * scij;
    float l = 0.5f * (expf(wll[idx]) * scij + expf(wll[ji]) * sc[ji]);
    eb = fmaf(b, b, eb); ef = fmaf(f, f, ef); el = fmaf(l, l, el);
  }
  wave_reduce3(eb, ef, el);
  __shared__ float red[3][4];
  int lane = threadIdx.x & 63, wv = threadIdx.x >> 6;
  if (lane == 0) { red[0][wv] = eb; red[1][wv] = ef; red[2][wv] = el; }
  __syncthreads();
  if (threadIdx.x == 0) {
    part[blockIdx.x]       = red[0][0] + red[0][1] + red[0][2] + red[0][3];
    part[64 + blockIdx.x]  = red[1][0] + red[1][1] + red[1][2] + red[1][3];
    part[128 + blockIdx.x] = red[2][0] + red[2][1] + red[2][2] + red[2][3];
  }
}

// ---------------------------------------------------------------------------
// Kernel B: TWO nodes per block, 32-lane halves share one instruction stream.
// r5 changes vs r4 (r4 exposed ~150cy LDS broadcast latency every step):
//  - per-lane transcendentals (6 exp2 + 6 rcp, replicated) -> no sigma/m
//    broadcast at all
//  - harvest t1/t2/t3 swizzled at END of step t-1 (right after ring update
//    makes P[0]=a(t)), consumed at END of step t (E/N0 updates) -> a full
//    step of issue->wait distance, zero exposed LDS latency
//  - U values preloaded per trial (10 statically-indexed ds_reads)
// ---------------------------------------------------------------------------
__global__ __launch_bounds__(128) void sim_kernel(
    const float* __restrict__ external, const float* __restrict__ hx,
    const float* __restrict__ hE, const float* __restrict__ sc,
    const float* __restrict__ dist, const float* __restrict__ wbb,
    const float* __restrict__ wff, const float* __restrict__ wll,
    const float* __restrict__ theta, const float* __restrict__ part,
    float* __restrict__ vsnap) {
  const int wv = threadIdx.x >> 6;
  const int lane = threadIdx.x & 63;
  const int node = blockIdx.x * 2 + wv;   // this wave's setup node

  __shared__ float Wall[2][3 * WSTR];   // per node: Wl | Wf | Wb (pre-scaled)
  __shared__ float hE_lds[2][DMAX];
  __shared__ float u_lds[2][STEPS * TRS];
  __shared__ float sc_c[2][3];          // rl, rf, rb (scaled row sums)
  __shared__ int   sc_md[2];            // per-node maxd

  // --- global norm sums from ssq partials (one DPP reduce) ---
  float sb = part[lane], sf = part[64 + lane], sl = part[128 + lane];
  wave_reduce3(sb, sf, sl);
  const float inv_nb = 1.f / sqrtf(sb);
  const float inv_nf = 1.f / sqrtf(sf);
  const float inv_nl = 1.f / sqrtf(sl);

  // --- parameters ---
  const float VL = relu_(theta[0]), VI = relu_(theta[1]);
  const float VE = relu_(theta[2]), VNMDA = relu_(theta[3]);
  const float alpha_mg = relu_(theta[4]), VR = relu_(theta[5]);
  const float pi_sigma = relu_(theta[6]);
  const float gLp = relu_(theta[7]), Cc = relu_(theta[8]), kappa = relu_(theta[9]);
  const float g_gE = relu_(theta[10]), g_gE_sc = relu_(theta[11]);
  const float g_gI = relu_(theta[12]), g_gI_sc = relu_(theta[13]);
  const float g_gN = relu_(theta[14]), g_gN_sc = relu_(theta[15]);
  const float g_k = relu_(theta[16]);
  const float mu = 0.1f + relu_(theta[20]);
  const float uk = relu_(theta[21]) * theta[23];
  const float g_l = relu_(theta[24]), g_f = relu_(theta[25]), g_b = relu_(theta[26]);
  const float DTC = DT / Cc;
  const float dk = DT * kappa;
  const float nps = -pi_sigma, psVR = pi_sigma * VR;
  const float nam = -alpha_mg;

  const float dk1  = 1.f - dk;
  const float cA   = dk * g_l;     // folded into Wl bins
  const float cF   = dk * g_f;     // folded into Wf bins
  const float cB   = dk * g_b;     // folded into Wb bins
  const float cE0s = dk * g_gE;
  const float cE1e = dk * g_gE_sc;
  const float cE2e = dk * g_k;
  const float cI0  = dk * g_gI;
  const float cI1  = dk * g_gI_sc;
  const float cN0s = dk * g_gN;
  const float cN1  = dk * g_gN_sc;
  const float cN2  = dk * g_gN;
  const float gLVL = gLp * VL;
  const float L2E = 1.44269504088896f;
  const float npsL2 = nps * L2E;
  const float namL2 = nam * L2E;

  // --- stage LDS (wave w handles node w's slabs) ---
  for (int k = lane; k < 3 * WSTR; k += 64) Wall[wv][k] = 0.f;
  for (int d = lane; d < DMAX; d += 64) hE_lds[wv][d] = hE[node * DMAX + d];
  const float ukdk = dk * uk;
  for (int t = lane; t < STEPS * TRS; t += 64)
    u_lds[wv][t] = ukdk * external[node * STEPS * TRS + t];

  // --- bin weights by delay (pre-scaled), row sums, max delay ---
  const float scl = inv_nl * cA, scf = inv_nf * cF, scb = inv_nb * cB;
  float rl = 0.f, rf = 0.f, rb = 0.f;
  int mymax = 0;
#pragma unroll
  for (int kj = 0; kj < JPL; ++kj) {
    int j = lane + kj * 64;
    if (j < NODE) {
      int ij = node * NODE + j;
      int ji = j * NODE + node;
      float scij = sc[ij];
      float vb = expf(wbb[ij]) * scij * scb;
      float vf = expf(wff[ij]) * scij * scf;
      float vl = 0.5f * (expf(wll[ij]) * scij + expf(wll[ji]) * sc[ji]) * scl;
      int dd = (int)(dist[ij] / mu);
      dd = min(max(dd, 0), DMAX - 1);
      atomicAdd(&Wall[wv][dd], vl);
      atomicAdd(&Wall[wv][WSTR + dd], vf);
      atomicAdd(&Wall[wv][2 * WSTR + dd], vb);
      rl += vl; rf += vf; rb += vb;
      mymax = max(mymax, dd);
    }
  }
  wave_reduce3(rl, rf, rb);
  const int maxd_w = wave_max_int(mymax);
  if (lane == 0) {
    sc_c[wv][0] = rl; sc_c[wv][1] = rf; sc_c[wv][2] = rb;
    sc_md[wv] = maxd_w;
  }
  __syncthreads();
  const int maxd = max(sc_md[0], sc_md[1]);

  if (maxd <= 126) {
    // ================= FAST PATH: wave 0 only, 32-lane halves ==============
    if (wv != 0) return;
    const int h = lane >> 5, hlane = lane & 31;
    const int nodeF = blockIdx.x * 2 + h;

    // per-lane (per-node) coefficients (VGPR by construction)
    const float rlh = sc_c[h][0], rfh = sc_c[h][1], rbh = sc_c[h][2];
    const float cE0s2 = cE0s - rlh;
    const float cN0s2 = cN0s - rlh;
    const float cE1s = -rbh;
    const float cE2s = -rfh;
    float vngLVL = -gLVL;      PIN_V(vngLVL);
    float vpsVRL2 = psVR * L2E; PIN_V(vpsVRL2);

    // initial state (replicated within half)
    const int hb = nodeF * POP * 4;
    float V0 = hx[hb + 0], V1 = hx[hb + 4], V2 = hx[hb + 8];
    float E0 = hx[hb + 1], E1 = hx[hb + 5], E2 = hx[hb + 9];
    float I0 = hx[hb + 2], I1 = hx[hb + 6], I2 = hx[hb + 10];
    float N0 = hx[hb + 3], N1 = hx[hb + 7], N2 = hx[hb + 11];

    const bool htop = (hlane == 31);

    // static per-lane weights: slot s = 4*hlane + r
    constexpr int NR = 4;
    float Wl[NR], Wf[NR], Wb[NR];
#pragma unroll
    for (int r = 0; r < NR; ++r) {
      int s = NR * hlane + r;
      Wl[r] = Wall[h][s];
      Wf[r] = Wall[h][WSTR + s];
      Wb[r] = Wall[h][2 * WSTR + s];
    }

    // prologue: P[slot s] = sum_{d>=s} W[d]*hE[d-s]
    float Pl[NR], Pf[NR], Pb[NR], hbuf[NR];
#pragma unroll
    for (int r = 0; r < NR; ++r) { Pl[r] = 0.f; Pf[r] = 0.f; Pb[r] = 0.f; hbuf[r] = 0.f; }
    for (int d = 0; d <= maxd; ++d) {
      float wl_ = Wall[h][d], wf_ = Wall[h][WSTR + d], wb_ = Wall[h][2 * WSTR + d];
#pragma unroll
      for (int r = NR - 1; r > 0; --r) hbuf[r] = hbuf[r - 1];
      int idx = d - NR * hlane;
      bool ok = idx >= 0;
      float hv = hE_lds[h][ok ? idx : 0];
      hbuf[0] = ok ? hv : 0.f;
#pragma unroll
      for (int r = 0; r < NR; ++r) {
        Pl[r] = fmaf(wl_, hbuf[r], Pl[r]);
        Pf[r] = fmaf(wf_, hbuf[r], Pf[r]);
        Pb[r] = fmaf(wb_, hbuf[r], Pb[r]);
      }
    }

    const float* uh = &u_lds[h][0];

    // pipelined harvest: issue swizzles for a(0) now, consume in step 0
    float t1 = swz_<0>(Pl[0]);
    float t2 = swz_<0>(Pf[0]);
    float t3 = swz_<0>(Pb[0]);

    for (int tr = 0; tr < TRS; ++tr) {
      // preload this trial's 10 drive values (statically indexed -> regs)
      float uu[STEPS];
#pragma unroll
      for (int s2 = 0; s2 < STEPS; ++s2) uu[s2] = uh[s2 * TRS + tr];
#pragma unroll
      for (int st = 0; st < STEPS; ++st) {
        // 1) per-lane sigmoids + mN (replicated; covers both halves)
        float sE = rcp_(1.f + __builtin_amdgcn_exp2f(fmaf(npsL2, V0, vpsVRL2)));
        float sI = rcp_(1.f + __builtin_amdgcn_exp2f(fmaf(npsL2, V1, vpsVRL2)));
        float sP = rcp_(1.f + __builtin_amdgcn_exp2f(fmaf(npsL2, V2, vpsVRL2)));
        float m0 = rcp_(fmaf(0.2f, __builtin_amdgcn_exp2f(namL2 * V0), 1.f));
        float m1 = rcp_(fmaf(0.2f, __builtin_amdgcn_exp2f(namL2 * V1), 1.f));
        float m2 = rcp_(fmaf(0.2f, __builtin_amdgcn_exp2f(namL2 * V2), 1.f));

        // 2) ring rotate(rename)+scatter: new P[r] = old P[r+1] + W[r]*sP
        float nll = htop ? 0.f : wrol1(Pl[0]);
        float nlf = htop ? 0.f : wrol1(Pf[0]);
        float nlb = htop ? 0.f : wrol1(Pb[0]);
        Pl[0] = fmaf(Wl[0], sP, Pl[1]);
        Pl[1] = fmaf(Wl[1], sP, Pl[2]);
        Pl[2] = fmaf(Wl[2], sP, Pl[3]);
        Pl[3] = fmaf(Wl[3], sP, nll);
        Pf[0] = fmaf(Wf[0], sP, Pf[1]);
        Pf[1] = fmaf(Wf[1], sP, Pf[2]);
        Pf[2] = fmaf(Wf[2], sP, Pf[3]);
        Pf[3] = fmaf(Wf[3], sP, nlf);
        Pb[0] = fmaf(Wb[0], sP, Pb[1]);
        Pb[1] = fmaf(Wb[1], sP, Pb[2]);
        Pb[2] = fmaf(Wb[2], sP, Pb[3]);
        Pb[3] = fmaf(Wb[3], sP, nlb);

        // 3) V/I/N updates (use OLD E/I/N; t-independent)
        float Nm0 = N0 * m0, Nm1 = N1 * m1, Nm2 = N2 * m2;
        float R0 = fmaf(E0, VE, fmaf(Nm0, VNMDA, fmaf(I0, -VI, vngLVL)));
        float R1 = fmaf(E1, VE, fmaf(Nm1, VNMDA, fmaf(I1, -VI, vngLVL)));
        float R2 = fmaf(E2, VE, fmaf(Nm2, VNMDA, fmaf(I2, -VI, vngLVL)));
        float S0 = gLp + E0 + I0 + Nm0;
        float S1 = gLp + E1 + I1 + Nm1;
        float S2 = gLp + E2 + I2 + Nm2;
        V0 = fmaf(DTC, fmaf(-S0, V0, R0), V0);
        V1 = fmaf(DTC, fmaf(-S1, V1, R1), V1);
        V2 = fmaf(DTC, fmaf(-S2, V2, R2), V2);
        float pI = cI0 * sI;
        I0 = fmaf(dk1, I0, pI);
        I1 = fmaf(dk1, I1, cI1 * sI);
        I2 = fmaf(dk1, I2, pI);
        N1 = fmaf(dk1, N1, cN1 * sE);
        N2 = fmaf(dk1, N2, cN2 * sE);

        // 4) t-consumers LAST (t1/t2/t3 issued a full step ago -> hidden)
        float U = uu[st];
        float T0 = t1 + U;
        float T2 = t2 + U;
        E0 = fmaf(dk1, E0, fmaf(cE0s2, sP, T0));
        E1 = fmaf(dk1, E1, fmaf(cE1e, sE, fmaf(cE1s, sP, t3)));
        E2 = fmaf(dk1, E2, fmaf(cE2e, sE, fmaf(cE2s, sP, T2)));
        N0 = fmaf(dk1, N0, fmaf(cN0s2, sP, t1));

        // 5) issue next step's harvest (P[0] now holds a(t+1))
        t1 = swz_<0>(Pl[0]);
        t2 = swz_<0>(Pf[0]);
        t3 = swz_<0>(Pb[0]);
      }
      if (hlane == 0) vsnap[tr * NODE + nodeF] = V2;
    }
    return;
  }

  // ================= SLOW PATH (maxd>126): r3 core, wave w = node w ========
  {
    const float cE0s2 = cE0s - rl;
    const float cN0s2 = cN0s - rl;
    const float cE1s = -rb;
    const float cE2s = -rf;

    const int hb = node * POP * 4;
    float V0 = hx[hb + 0], V1 = hx[hb + 4], V2 = hx[hb + 8];
    float E0 = hx[hb + 1], E1 = hx[hb + 5], E2 = hx[hb + 9];
    float I0 = hx[hb + 2], I1 = hx[hb + 6], I2 = hx[hb + 10];
    float N0 = hx[hb + 3], N1 = hx[hb + 7], N2 = hx[hb + 11];

    const bool loS = (lane < 3);
    const float caL = loS ? npsL2 : namL2;
    const float cbL = loS ? psVR * L2E : 0.f;
    const float cdL = loS ? 1.f : 0.2f;
    const bool selB = (lane == 1) || (lane == 4);
    const bool selC = (lane == 2) || (lane == 5);
    const bool is63 = (lane == 63);

    float vE0s2 = cE0s2; PIN_V(vE0s2);
    float vN0s2 = cN0s2; PIN_V(vN0s2);
    float vE1e  = cE1e;  PIN_V(vE1e);
    float vE1s  = cE1s;  PIN_V(vE1s);
    float vE2e  = cE2e;  PIN_V(vE2e);
    float vE2s  = cE2s;  PIN_V(vE2s);
    float vI0   = cI0;   PIN_V(vI0);
    float vI1   = cI1;   PIN_V(vI1);
    float vN1   = cN1;   PIN_V(vN1);
    float vN2   = cN2;   PIN_V(vN2);
    float vngLVL = -gLVL; PIN_V(vngLVL);

    constexpr int NR = 8;
    float Wl[NR], Wf[NR], Wb[NR];
#pragma unroll
    for (int r = 0; r < NR; ++r) {
      int s = NR * lane + r;
      Wl[r] = Wall[wv][s];
      Wf[r] = Wall[wv][WSTR + s];
      Wb[r] = Wall[wv][2 * WSTR + s];
    }

    float Pl[NR], Pf[NR], Pb[NR], hbuf[NR];
#pragma unroll
    for (int r = 0; r < NR; ++r) { Pl[r] = 0.f; Pf[r] = 0.f; Pb[r] = 0.f; hbuf[r] = 0.f; }
    for (int d = 0; d <= maxd; ++d) {
      float wl_ = Wall[wv][d], wf_ = Wall[wv][WSTR + d], wb_ = Wall[wv][2 * WSTR + d];
#pragma unroll
      for (int r = NR - 1; r > 0; --r) hbuf[r] = hbuf[r - 1];
      int idx = d - NR * lane;
      bool ok = idx >= 0;
      float hv = hE_lds[wv][ok ? idx : 0];
      hbuf[0] = ok ? hv : 0.f;
#pragma unroll
      for (int r = 0; r < NR; ++r) {
        Pl[r] = fmaf(wl_, hbuf[r], Pl[r]);
        Pf[r] = fmaf(wf_, hbuf[r], Pf[r]);
        Pb[r] = fmaf(wb_, hbuf[r], Pb[r]);
      }
    }

    auto rotscat = [&](float* P, const float* W, float sPv) {
      float nl = is63 ? 0.f : wrol1(P[0]);
#pragma unroll
      for (int r = 0; r < NR - 1; ++r) P[r] = fmaf(W[r], sPv, P[r + 1]);
      P[NR - 1] = fmaf(W[NR - 1], sPv, nl);
    };

    for (int tr = 0; tr < TRS; ++tr) {
      float u_tr = (lane < STEPS) ? u_lds[wv][lane * TRS + tr] : 0.f;
#pragma unroll
      for (int st = 0; st < STEPS; ++st) {
        float t1 = bperm0_(Pl[0]);
        float t2 = bperm0_(Pf[0]);
        float t3 = bperm0_(Pb[0]);

        float Vs = selC ? V2 : (selB ? V1 : V0);
        float ex = __builtin_amdgcn_exp2f(fmaf(caL, Vs, cbL));
        float sg = rcp_(fmaf(cdL, ex, 1.f));
        float sE = rlane_(sg, 0), sI = rlane_(sg, 1), sP = rlane_(sg, 2);
        float m0 = rlane_(sg, 3), m1 = rlane_(sg, 4), m2 = rlane_(sg, 5);
        float U = rlane_(u_tr, st);

        float T0 = t1 + U;
        float T2 = t2 + U;
        float nE0 = fmaf(dk1, E0, fmaf(vE0s2, sP, T0));
        float nN0 = fmaf(dk1, N0, fmaf(vN0s2, sP, t1));
        float nE1 = fmaf(dk1, E1, fmaf(vE1e, sE, fmaf(vE1s, sP, t3)));
        float nN1 = fmaf(dk1, N1, vN1 * sE);
        float nE2 = fmaf(dk1, E2, fmaf(vE2e, sE, fmaf(vE2s, sP, T2)));
        float nN2 = fmaf(dk1, N2, vN2 * sE);
        float pI = vI0 * sI;
        float nI0 = fmaf(dk1, I0, pI);
        float nI1 = fmaf(dk1, I1, vI1 * sI);
        float nI2 = fmaf(dk1, I2, pI);

        float Nm0 = N0 * m0, Nm1 = N1 * m1, Nm2 = N2 * m2;
        float R0 = fmaf(E0, VE, fmaf(Nm0, VNMDA, fmaf(I0, -VI, vngLVL)));
        float R1 = fmaf(E1, VE, fmaf(Nm1, VNMDA, fmaf(I1, -VI, vngLVL)));
        float R2 = fmaf(E2, VE, fmaf(Nm2, VNMDA, fmaf(I2, -VI, vngLVL)));
        float S0 = gLp + E0 + I0 + Nm0;
        float S1 = gLp + E1 + I1 + Nm1;
        float S2 = gLp + E2 + I2 + Nm2;
        V0 = fmaf(DTC, fmaf(-S0, V0, R0), V0);
        V1 = fmaf(DTC, fmaf(-S1, V1, R1), V1);
        V2 = fmaf(DTC, fmaf(-S2, V2, R2), V2);
        E0 = nE0; E1 = nE1; E2 = nE2;
        I0 = nI0; I1 = nI1; I2 = nI2;
        N0 = nN0; N1 = nN1; N2 = nN2;

        rotscat(Pl, Wl, sP);
        rotscat(Pf, Wf, sP);
        rotscat(Pb, Wb, sP);
      }
      if (lane == 0) vsnap[tr * NODE + node] = V2;
    }
  }
}

// ---------------------------------------------------------------------------
// Kernel C: EEG readout. cm elimination: sum((lm-cm)@v) = a_o - mean_o(a_o).
// ---------------------------------------------------------------------------
__global__ __launch_bounds__(256) void eeg_kernel(
    const float* __restrict__ lm, const float* __restrict__ vsnap,
    const float* __restrict__ theta, float* __restrict__ out) {
  int tr = blockIdx.x;
  __shared__ float vs[NODE];
  __shared__ float partl[4][OUT];
  int tid = threadIdx.x;
  for (int n = tid; n < NODE; n += 256) vs[n] = vsnap[tr * NODE + n];
  __syncthreads();
  int o = tid & 63, w = tid >> 6;
  float acc = 0.f;
  for (int n = w * 100; n < w * 100 + 100; ++n)
    acc = fmaf(lm[o * NODE + n], vs[n], acc);
  partl[w][o] = acc;
  __syncthreads();
  if (tid < OUT) {
    float cy0 = theta[22], y0 = theta[19];
    float a = partl[0][tid] + partl[1][tid] + partl[2][tid] + partl[3][tid];
    float mean = wave_reduce1(a) * (1.f / OUT);
    out[tr * OUT + tid] = cy0 * (a - mean) - y0;
  }
}

extern "C" void kernel_launch(void* const* d_in, const int* in_sizes, int n_in,
                              void* d_out, int out_size, void* d_ws, size_t ws_size,
                              hipStream_t stream) {
  const float* external = (const float*)d_in[0];
  const float* hx       = (const float*)d_in[1];
  const float* hE       = (const float*)d_in[2];
  const float* sc       = (const float*)d_in[3];
  const float* dist     = (const float*)d_in[4];
  const float* wbb      = (const float*)d_in[5];
  const float* wff      = (const float*)d_in[6];
  const float* wll      = (const float*)d_in[7];
  const float* lm       = (const float*)d_in[8];
  const float* theta    = (const float*)d_in[9];
  float* out = (float*)d_out;

  float* vsnap = (float*)d_ws;               // TRS*NODE
  float* part  = vsnap + TRS * NODE;         // 3*64 ssq partials

  ssq_kernel<<<64, 256, 0, stream>>>(wbb, wff, wll, sc, part);
  sim_kernel<<<NODE / 2, 128, 0, stream>>>(external, hx, hE, sc, dist, wbb, wff,
                                           wll, theta, part, vsnap);
  eeg_kernel<<<TRS, 256, 0, stream>>>(lm, vsnap, theta, out);
}

// Round 6
// 171.361 us; speedup vs baseline: 1.4178x; 1.0142x over previous
//
#include <hip/hip_runtime.h>
#include <type_traits>

#define NODE 400
#define POP 3
#define TRS 40
#define STEPS 10
#define DMAX 500
#define OUT 64
#define DT 0.1f
#define JPL 7           // ceil(NODE/64) j-indices per lane
#define WSTR 512        // per-stream W bin stride (delta in [0,511])

__device__ __forceinline__ float relu_(float x) { return x > 0.f ? x : 0.f; }
__device__ __forceinline__ float rcp_(float x) { return __builtin_amdgcn_rcpf(x); }
__device__ __forceinline__ float rlane_(float v, int l) {
  return __builtin_bit_cast(float, __builtin_amdgcn_readlane(__builtin_bit_cast(int, v), l));
}
// broadcast lane 0 to all lanes, VGPR result (slow-path harvest)
__device__ __forceinline__ float bperm0_(float v) {
  return __builtin_bit_cast(float,
      __builtin_amdgcn_ds_bpermute(0, __builtin_bit_cast(int, v)));
}
// ds_swizzle BitMode: src_lane = ((lane & and) | or) ^ xor within each
// 32-lane group. OFF = (xor<<10)|(or<<5)|and. OFF=0 -> every lane reads
// lane 0 of its OWN 32-group (half-local broadcast).
template <int OFF>
__device__ __forceinline__ float swz_(float v) {
  return __builtin_bit_cast(float,
      __builtin_amdgcn_ds_swizzle(__builtin_bit_cast(int, v), OFF));
}
// pin a value into a VGPR
#define PIN_V(x) asm volatile("" : "+v"(x))

// ---- DPP helpers
template <int CTRL>
__device__ __forceinline__ float dpp_mov(float x) {
  int r = __builtin_amdgcn_update_dpp(0, __builtin_bit_cast(int, x), CTRL,
                                      0xf, 0xf, true);
  return __builtin_bit_cast(float, r);
}
template <int CTRL>
__device__ __forceinline__ int dpp_movi(int x) {
  return __builtin_amdgcn_update_dpp(0, x, CTRL, 0xf, 0xf, true);
}
// wave rotate: dst[L] = src[(L+1) & 63]  (wave_rol:1 = 0x134, verified r1-r5)
__device__ __forceinline__ float wrol1(float x) { return dpp_mov<0x134>(x); }

__device__ __forceinline__ void wave_reduce3(float& a, float& b, float& c) {
  a += dpp_mov<0x111>(a); b += dpp_mov<0x111>(b); c += dpp_mov<0x111>(c);
  a += dpp_mov<0x112>(a); b += dpp_mov<0x112>(b); c += dpp_mov<0x112>(c);
  a += dpp_mov<0x114>(a); b += dpp_mov<0x114>(b); c += dpp_mov<0x114>(c);
  a += dpp_mov<0x118>(a); b += dpp_mov<0x118>(b); c += dpp_mov<0x118>(c);
  a += dpp_mov<0x142>(a); b += dpp_mov<0x142>(b); c += dpp_mov<0x142>(c);
  a += dpp_mov<0x143>(a); b += dpp_mov<0x143>(b); c += dpp_mov<0x143>(c);
  a = rlane_(a, 63); b = rlane_(b, 63); c = rlane_(c, 63);
}

__device__ __forceinline__ float wave_reduce1(float a) {
  a += dpp_mov<0x111>(a); a += dpp_mov<0x112>(a); a += dpp_mov<0x114>(a);
  a += dpp_mov<0x118>(a); a += dpp_mov<0x142>(a); a += dpp_mov<0x143>(a);
  return rlane_(a, 63);
}

__device__ __forceinline__ int wave_max_int(int x) {
  x = max(x, dpp_movi<0x111>(x));
  x = max(x, dpp_movi<0x112>(x));
  x = max(x, dpp_movi<0x114>(x));
  x = max(x, dpp_movi<0x118>(x));
  x = max(x, dpp_movi<0x142>(x));
  x = max(x, dpp_movi<0x143>(x));
  return __builtin_amdgcn_readlane(x, 63);
}

// ---------------------------------------------------------------------------
// Kernel A: Frobenius sum-of-squares partials (64 blocks, no atomics).
// ---------------------------------------------------------------------------
__global__ __launch_bounds__(256) void ssq_kernel(
    const float* __restrict__ wbb, const float* __restrict__ wff,
    const float* __restrict__ wll, const float* __restrict__ sc,
    float* __restrict__ part) {
  float eb = 0.f, ef = 0.f, el = 0.f;
  for (int idx = blockIdx.x * 256 + threadIdx.x; idx < NODE * NODE;
       idx += 64 * 256) {
    int i = idx / NODE, j = idx - i * NODE;
    int ji = j * NODE + i;
    float scij = sc[idx];
    float b = expf(wbb[idx]) * scij;
    float f = expf(wff[idx]) * scij;
    float l = 0.5f * (expf(wll[idx]) * scij + expf(wll[ji]) * sc[ji]);
    eb = fmaf(b, b, eb); ef = fmaf(f, f, ef); el = fmaf(l, l, el);
  }
  wave_reduce3(eb, ef, el);
  __shared__ float red[3][4];
  int lane = threadIdx.x & 63, wv = threadIdx.x >> 6;
  if (lane == 0) { red[0][wv] = eb; red[1][wv] = ef; red[2][wv] = el; }
  __syncthreads();
  if (threadIdx.x == 0) {
    part[blockIdx.x]       = red[0][0] + red[0][1] + red[0][2] + red[0][3];
    part[64 + blockIdx.x]  = red[1][0] + red[1][1] + red[1][2] + red[1][3];
    part[128 + blockIdx.x] = red[2][0] + red[2][1] + red[2][2] + red[2][3];
  }
}

// ---------------------------------------------------------------------------
// Kernel B: TWO nodes per block, 32-lane halves share one instruction stream.
// r6 vs r5: dynamics are only REQUIRED to be correct on lane 0 of each half
// (lane 0 / lane 32): the ring stays correct on all lanes via the broadcast
// sP, vsnap is written from lane 0, and sP itself is broadcast FROM lane 0.
// So: harvest t1/t2/t3 = P[0] read LOCALLY (0 ops, no LDS), and only ONE
// ds_swizzle per step (sP broadcast), consumed only by the ring scatter and
// separated from its issue by the ~33-op V/I/N update block. Other lanes'
// dynamics drift to garbage harmlessly.
// ---------------------------------------------------------------------------
__global__ __launch_bounds__(128) void sim_kernel(
    const float* __restrict__ external, const float* __restrict__ hx,
    const float* __restrict__ hE, const float* __restrict__ sc,
    const float* __restrict__ dist, const float* __restrict__ wbb,
    const float* __restrict__ wff, const float* __restrict__ wll,
    const float* __restrict__ theta, const float* __restrict__ part,
    float* __restrict__ vsnap) {
  const int wv = threadIdx.x >> 6;
  const int lane = threadIdx.x & 63;
  const int node = blockIdx.x * 2 + wv;   // this wave's setup node

  __shared__ float Wall[2][3 * WSTR];   // per node: Wl | Wf | Wb (pre-scaled)
  __shared__ float hE_lds[2][DMAX];
  __shared__ float u_lds[2][STEPS * TRS];
  __shared__ float sc_c[2][3];          // rl, rf, rb (scaled row sums)
  __shared__ int   sc_md[2];            // per-node maxd

  // --- global norm sums from ssq partials (one DPP reduce) ---
  float sb = part[lane], sf = part[64 + lane], sl = part[128 + lane];
  wave_reduce3(sb, sf, sl);
  const float inv_nb = 1.f / sqrtf(sb);
  const float inv_nf = 1.f / sqrtf(sf);
  const float inv_nl = 1.f / sqrtf(sl);

  // --- parameters ---
  const float VL = relu_(theta[0]), VI = relu_(theta[1]);
  const float VE = relu_(theta[2]), VNMDA = relu_(theta[3]);
  const float alpha_mg = relu_(theta[4]), VR = relu_(theta[5]);
  const float pi_sigma = relu_(theta[6]);
  const float gLp = relu_(theta[7]), Cc = relu_(theta[8]), kappa = relu_(theta[9]);
  const float g_gE = relu_(theta[10]), g_gE_sc = relu_(theta[11]);
  const float g_gI = relu_(theta[12]), g_gI_sc = relu_(theta[13]);
  const float g_gN = relu_(theta[14]), g_gN_sc = relu_(theta[15]);
  const float g_k = relu_(theta[16]);
  const float mu = 0.1f + relu_(theta[20]);
  const float uk = relu_(theta[21]) * theta[23];
  const float g_l = relu_(theta[24]), g_f = relu_(theta[25]), g_b = relu_(theta[26]);
  const float DTC = DT / Cc;
  const float dk = DT * kappa;
  const float nps = -pi_sigma, psVR = pi_sigma * VR;
  const float nam = -alpha_mg;

  const float dk1  = 1.f - dk;
  const float cA   = dk * g_l;     // folded into Wl bins
  const float cF   = dk * g_f;     // folded into Wf bins
  const float cB   = dk * g_b;     // folded into Wb bins
  const float cE0s = dk * g_gE;
  const float cE1e = dk * g_gE_sc;
  const float cE2e = dk * g_k;
  const float cI0  = dk * g_gI;
  const float cI1  = dk * g_gI_sc;
  const float cN0s = dk * g_gN;
  const float cN1  = dk * g_gN_sc;
  const float cN2  = dk * g_gN;
  const float gLVL = gLp * VL;
  const float L2E = 1.44269504088896f;
  const float npsL2 = nps * L2E;
  const float namL2 = nam * L2E;

  // --- stage LDS (wave w handles node w's slabs) ---
  for (int k = lane; k < 3 * WSTR; k += 64) Wall[wv][k] = 0.f;
  for (int d = lane; d < DMAX; d += 64) hE_lds[wv][d] = hE[node * DMAX + d];
  const float ukdk = dk * uk;
  for (int t = lane; t < STEPS * TRS; t += 64)
    u_lds[wv][t] = ukdk * external[node * STEPS * TRS + t];

  // --- bin weights by delay (pre-scaled), row sums, max delay ---
  const float scl = inv_nl * cA, scf = inv_nf * cF, scb = inv_nb * cB;
  float rl = 0.f, rf = 0.f, rb = 0.f;
  int mymax = 0;
#pragma unroll
  for (int kj = 0; kj < JPL; ++kj) {
    int j = lane + kj * 64;
    if (j < NODE) {
      int ij = node * NODE + j;
      int ji = j * NODE + node;
      float scij = sc[ij];
      float vb = expf(wbb[ij]) * scij * scb;
      float vf = expf(wff[ij]) * scij * scf;
      float vl = 0.5f * (expf(wll[ij]) * scij + expf(wll[ji]) * sc[ji]) * scl;
      int dd = (int)(dist[ij] / mu);
      dd = min(max(dd, 0), DMAX - 1);
      atomicAdd(&Wall[wv][dd], vl);
      atomicAdd(&Wall[wv][WSTR + dd], vf);
      atomicAdd(&Wall[wv][2 * WSTR + dd], vb);
      rl += vl; rf += vf; rb += vb;
      mymax = max(mymax, dd);
    }
  }
  wave_reduce3(rl, rf, rb);
  const int maxd_w = wave_max_int(mymax);
  if (lane == 0) {
    sc_c[wv][0] = rl; sc_c[wv][1] = rf; sc_c[wv][2] = rb;
    sc_md[wv] = maxd_w;
  }
  __syncthreads();
  const int maxd = max(sc_md[0], sc_md[1]);

  if (maxd <= 126) {
    // ================= FAST PATH: wave 0 only, 32-lane halves ==============
    if (wv != 0) return;
    const int h = lane >> 5, hlane = lane & 31;
    const int nodeF = blockIdx.x * 2 + h;

    // per-lane (per-node) coefficients (VGPR by construction)
    const float rlh = sc_c[h][0], rfh = sc_c[h][1], rbh = sc_c[h][2];
    const float cE0s2 = cE0s - rlh;
    const float cN0s2 = cN0s - rlh;
    const float cE1s = -rbh;
    const float cE2s = -rfh;
    float vngLVL = -gLVL;      PIN_V(vngLVL);
    float vpsVRL2 = psVR * L2E; PIN_V(vpsVRL2);

    // initial state (replicated within half; only lane 0/32's copy stays true)
    const int hb = nodeF * POP * 4;
    float V0 = hx[hb + 0], V1 = hx[hb + 4], V2 = hx[hb + 8];
    float E0 = hx[hb + 1], E1 = hx[hb + 5], E2 = hx[hb + 9];
    float I0 = hx[hb + 2], I1 = hx[hb + 6], I2 = hx[hb + 10];
    float N0 = hx[hb + 3], N1 = hx[hb + 7], N2 = hx[hb + 11];

    const bool htop = (hlane == 31);

    // static per-lane weights: slot s = 4*hlane + r
    constexpr int NR = 4;
    float Wl[NR], Wf[NR], Wb[NR];
#pragma unroll
    for (int r = 0; r < NR; ++r) {
      int s = NR * hlane + r;
      Wl[r] = Wall[h][s];
      Wf[r] = Wall[h][WSTR + s];
      Wb[r] = Wall[h][2 * WSTR + s];
    }

    // prologue: P[slot s] = sum_{d>=s} W[d]*hE[d-s]  (P[0] = a(0))
    float Pl[NR], Pf[NR], Pb[NR], hbuf[NR];
#pragma unroll
    for (int r = 0; r < NR; ++r) { Pl[r] = 0.f; Pf[r] = 0.f; Pb[r] = 0.f; hbuf[r] = 0.f; }
    for (int d = 0; d <= maxd; ++d) {
      float wl_ = Wall[h][d], wf_ = Wall[h][WSTR + d], wb_ = Wall[h][2 * WSTR + d];
#pragma unroll
      for (int r = NR - 1; r > 0; --r) hbuf[r] = hbuf[r - 1];
      int idx = d - NR * hlane;
      bool ok = idx >= 0;
      float hv = hE_lds[h][ok ? idx : 0];
      hbuf[0] = ok ? hv : 0.f;
#pragma unroll
      for (int r = 0; r < NR; ++r) {
        Pl[r] = fmaf(wl_, hbuf[r], Pl[r]);
        Pf[r] = fmaf(wf_, hbuf[r], Pf[r]);
        Pb[r] = fmaf(wb_, hbuf[r], Pb[r]);
      }
    }

    const float* uh = &u_lds[h][0];

    for (int tr = 0; tr < TRS; ++tr) {
      // preload this trial's 10 drive values (statically indexed -> regs)
      float uu[STEPS];
#pragma unroll
      for (int s2 = 0; s2 < STEPS; ++s2) uu[s2] = uh[s2 * TRS + tr];
#pragma unroll
      for (int st = 0; st < STEPS; ++st) {
        // B) harvest a(t) LOCALLY — valid on hlane 0, the only lane that
        //    matters for the dynamics (0 instructions, no LDS)
        float t1 = Pl[0], t2 = Pf[0], t3 = Pb[0];

        // C) per-lane sigmoids + mN (6 independent trans chains)
        float sP = rcp_(1.f + __builtin_amdgcn_exp2f(fmaf(npsL2, V2, vpsVRL2)));
        float sE = rcp_(1.f + __builtin_amdgcn_exp2f(fmaf(npsL2, V0, vpsVRL2)));
        float sI = rcp_(1.f + __builtin_amdgcn_exp2f(fmaf(npsL2, V1, vpsVRL2)));
        float m0 = rcp_(fmaf(0.2f, __builtin_amdgcn_exp2f(namL2 * V0), 1.f));
        float m1 = rcp_(fmaf(0.2f, __builtin_amdgcn_exp2f(namL2 * V1), 1.f));
        float m2 = rcp_(fmaf(0.2f, __builtin_amdgcn_exp2f(namL2 * V2), 1.f));

        // D) the ONE cross-lane op: broadcast lane-0's sP within each half;
        //    pin its issue point so it can't sink toward its use (r4 lesson)
        float sPbc = swz_<0>(sP);
        __builtin_amdgcn_sched_barrier(0);

        // E1) V/I/N updates (old E/I/N; local sigmoid values) — ~33 ops of
        //     separation covering the swizzle's LDS round trip
        float Nm0 = N0 * m0, Nm1 = N1 * m1, Nm2 = N2 * m2;
        float R0 = fmaf(E0, VE, fmaf(Nm0, VNMDA, fmaf(I0, -VI, vngLVL)));
        float R1 = fmaf(E1, VE, fmaf(Nm1, VNMDA, fmaf(I1, -VI, vngLVL)));
        float R2 = fmaf(E2, VE, fmaf(Nm2, VNMDA, fmaf(I2, -VI, vngLVL)));
        float S0 = gLp + E0 + I0 + Nm0;
        float S1 = gLp + E1 + I1 + Nm1;
        float S2 = gLp + E2 + I2 + Nm2;
        V0 = fmaf(DTC, fmaf(-S0, V0, R0), V0);
        V1 = fmaf(DTC, fmaf(-S1, V1, R1), V1);
        V2 = fmaf(DTC, fmaf(-S2, V2, R2), V2);
        float pI = cI0 * sI;
        I0 = fmaf(dk1, I0, pI);
        I1 = fmaf(dk1, I1, cI1 * sI);
        I2 = fmaf(dk1, I2, pI);
        N1 = fmaf(dk1, N1, cN1 * sE);
        N2 = fmaf(dk1, N2, cN2 * sE);

        // A) ring rotate(rename)+scatter with BROADCAST sP (all-lane correct)
        float nll = htop ? 0.f : wrol1(Pl[0]);
        float nlf = htop ? 0.f : wrol1(Pf[0]);
        float nlb = htop ? 0.f : wrol1(Pb[0]);
        Pl[0] = fmaf(Wl[0], sPbc, Pl[1]);
        Pl[1] = fmaf(Wl[1], sPbc, Pl[2]);
        Pl[2] = fmaf(Wl[2], sPbc, Pl[3]);
        Pl[3] = fmaf(Wl[3], sPbc, nll);
        Pf[0] = fmaf(Wf[0], sPbc, Pf[1]);
        Pf[1] = fmaf(Wf[1], sPbc, Pf[2]);
        Pf[2] = fmaf(Wf[2], sPbc, Pf[3]);
        Pf[3] = fmaf(Wf[3], sPbc, nlf);
        Pb[0] = fmaf(Wb[0], sPbc, Pb[1]);
        Pb[1] = fmaf(Wb[1], sPbc, Pb[2]);
        Pb[2] = fmaf(Wb[2], sPbc, Pb[3]);
        Pb[3] = fmaf(Wb[3], sPbc, nlb);

        // E2) t-consumers with LOCAL t1/t2/t3 + local sP/sE (lane-0 correct)
        float U = uu[st];
        float T0 = t1 + U;
        float T2 = t2 + U;
        E0 = fmaf(dk1, E0, fmaf(cE0s2, sP, T0));
        E1 = fmaf(dk1, E1, fmaf(cE1e, sE, fmaf(cE1s, sP, t3)));
        E2 = fmaf(dk1, E2, fmaf(cE2e, sE, fmaf(cE2s, sP, T2)));
        N0 = fmaf(dk1, N0, fmaf(cN0s2, sP, t1));
      }
      if (hlane == 0) vsnap[tr * NODE + nodeF] = V2;
    }
    return;
  }

  // ================= SLOW PATH (maxd>126): r3 core, wave w = node w ========
  {
    const float cE0s2 = cE0s - rl;
    const float cN0s2 = cN0s - rl;
    const float cE1s = -rb;
    const float cE2s = -rf;

    const int hb = node * POP * 4;
    float V0 = hx[hb + 0], V1 = hx[hb + 4], V2 = hx[hb + 8];
    float E0 = hx[hb + 1], E1 = hx[hb + 5], E2 = hx[hb + 9];
    float I0 = hx[hb + 2], I1 = hx[hb + 6], I2 = hx[hb + 10];
    float N0 = hx[hb + 3], N1 = hx[hb + 7], N2 = hx[hb + 11];

    const bool loS = (lane < 3);
    const float caL = loS ? npsL2 : namL2;
    const float cbL = loS ? psVR * L2E : 0.f;
    const float cdL = loS ? 1.f : 0.2f;
    const bool selB = (lane == 1) || (lane == 4);
    const bool selC = (lane == 2) || (lane == 5);
    const bool is63 = (lane == 63);

    float vE0s2 = cE0s2; PIN_V(vE0s2);
    float vN0s2 = cN0s2; PIN_V(vN0s2);
    float vE1e  = cE1e;  PIN_V(vE1e);
    float vE1s  = cE1s;  PIN_V(vE1s);
    float vE2e  = cE2e;  PIN_V(vE2e);
    float vE2s  = cE2s;  PIN_V(vE2s);
    float vI0   = cI0;   PIN_V(vI0);
    float vI1   = cI1;   PIN_V(vI1);
    float vN1   = cN1;   PIN_V(vN1);
    float vN2   = cN2;   PIN_V(vN2);
    float vngLVL = -gLVL; PIN_V(vngLVL);

    constexpr int NR = 8;
    float Wl[NR], Wf[NR], Wb[NR];
#pragma unroll
    for (int r = 0; r < NR; ++r) {
      int s = NR * lane + r;
      Wl[r] = Wall[wv][s];
      Wf[r] = Wall[wv][WSTR + s];
      Wb[r] = Wall[wv][2 * WSTR + s];
    }

    float Pl[NR], Pf[NR], Pb[NR], hbuf[NR];
#pragma unroll
    for (int r = 0; r < NR; ++r) { Pl[r] = 0.f; Pf[r] = 0.f; Pb[r] = 0.f; hbuf[r] = 0.f; }
    for (int d = 0; d <= maxd; ++d) {
      float wl_ = Wall[wv][d], wf_ = Wall[wv][WSTR + d], wb_ = Wall[wv][2 * WSTR + d];
#pragma unroll
      for (int r = NR - 1; r > 0; --r) hbuf[r] = hbuf[r - 1];
      int idx = d - NR * lane;
      bool ok = idx >= 0;
      float hv = hE_lds[wv][ok ? idx : 0];
      hbuf[0] = ok ? hv : 0.f;
#pragma unroll
      for (int r = 0; r < NR; ++r) {
        Pl[r] = fmaf(wl_, hbuf[r], Pl[r]);
        Pf[r] = fmaf(wf_, hbuf[r], Pf[r]);
        Pb[r] = fmaf(wb_, hbuf[r], Pb[r]);
      }
    }

    auto rotscat = [&](float* P, const float* W, float sPv) {
      float nl = is63 ? 0.f : wrol1(P[0]);
#pragma unroll
      for (int r = 0; r < NR - 1; ++r) P[r] = fmaf(W[r], sPv, P[r + 1]);
      P[NR - 1] = fmaf(W[NR - 1], sPv, nl);
    };

    for (int tr = 0; tr < TRS; ++tr) {
      float u_tr = (lane < STEPS) ? u_lds[wv][lane * TRS + tr] : 0.f;
#pragma unroll
      for (int st = 0; st < STEPS; ++st) {
        float t1 = bperm0_(Pl[0]);
        float t2 = bperm0_(Pf[0]);
        float t3 = bperm0_(Pb[0]);

        float Vs = selC ? V2 : (selB ? V1 : V0);
        float ex = __builtin_amdgcn_exp2f(fmaf(caL, Vs, cbL));
        float sg = rcp_(fmaf(cdL, ex, 1.f));
        float sE = rlane_(sg, 0), sI = rlane_(sg, 1), sP = rlane_(sg, 2);
        float m0 = rlane_(sg, 3), m1 = rlane_(sg, 4), m2 = rlane_(sg, 5);
        float U = rlane_(u_tr, st);

        float T0 = t1 + U;
        float T2 = t2 + U;
        float nE0 = fmaf(dk1, E0, fmaf(vE0s2, sP, T0));
        float nN0 = fmaf(dk1, N0, fmaf(vN0s2, sP, t1));
        float nE1 = fmaf(dk1, E1, fmaf(vE1e, sE, fmaf(vE1s, sP, t3)));
        float nN1 = fmaf(dk1, N1, vN1 * sE);
        float nE2 = fmaf(dk1, E2, fmaf(vE2e, sE, fmaf(vE2s, sP, T2)));
        float nN2 = fmaf(dk1, N2, vN2 * sE);
        float pI = vI0 * sI;
        float nI0 = fmaf(dk1, I0, pI);
        float nI1 = fmaf(dk1, I1, vI1 * sI);
        float nI2 = fmaf(dk1, I2, pI);

        float Nm0 = N0 * m0, Nm1 = N1 * m1, Nm2 = N2 * m2;
        float R0 = fmaf(E0, VE, fmaf(Nm0, VNMDA, fmaf(I0, -VI, vngLVL)));
        float R1 = fmaf(E1, VE, fmaf(Nm1, VNMDA, fmaf(I1, -VI, vngLVL)));
        float R2 = fmaf(E2, VE, fmaf(Nm2, VNMDA, fmaf(I2, -VI, vngLVL)));
        float S0 = gLp + E0 + I0 + Nm0;
        float S1 = gLp + E1 + I1 + Nm1;
        float S2 = gLp + E2 + I2 + Nm2;
        V0 = fmaf(DTC, fmaf(-S0, V0, R0), V0);
        V1 = fmaf(DTC, fmaf(-S1, V1, R1), V1);
        V2 = fmaf(DTC, fmaf(-S2, V2, R2), V2);
        E0 = nE0; E1 = nE1; E2 = nE2;
        I0 = nI0; I1 = nI1; I2 = nI2;
        N0 = nN0; N1 = nN1; N2 = nN2;

        rotscat(Pl, Wl, sP);
        rotscat(Pf, Wf, sP);
        rotscat(Pb, Wb, sP);
      }
      if (lane == 0) vsnap[tr * NODE + node] = V2;
    }
  }
}

// ---------------------------------------------------------------------------
// Kernel C: EEG readout. cm elimination: sum((lm-cm)@v) = a_o - mean_o(a_o).
// ---------------------------------------------------------------------------
__global__ __launch_bounds__(256) void eeg_kernel(
    const float* __restrict__ lm, const float* __restrict__ vsnap,
    const float* __restrict__ theta, float* __restrict__ out) {
  int tr = blockIdx.x;
  __shared__ float vs[NODE];
  __shared__ float partl[4][OUT];
  int tid = threadIdx.x;
  for (int n = tid; n < NODE; n += 256) vs[n] = vsnap[tr * NODE + n];
  __syncthreads();
  int o = tid & 63, w = tid >> 6;
  float acc = 0.f;
  for (int n = w * 100; n < w * 100 + 100; ++n)
    acc = fmaf(lm[o * NODE + n], vs[n], acc);
  partl[w][o] = acc;
  __syncthreads();
  if (tid < OUT) {
    float cy0 = theta[22], y0 = theta[19];
    float a = partl[0][tid] + partl[1][tid] + partl[2][tid] + partl[3][tid];
    float mean = wave_reduce1(a) * (1.f / OUT);
    out[tr * OUT + tid] = cy0 * (a - mean) - y0;
  }
}

extern "C" void kernel_launch(void* const* d_in, const int* in_sizes, int n_in,
                              void* d_out, int out_size, void* d_ws, size_t ws_size,
                              hipStream_t stream) {
  const float* external = (const float*)d_in[0];
  const float* hx       = (const float*)d_in[1];
  const float* hE       = (const float*)d_in[2];
  const float* sc       = (const float*)d_in[3];
  const float* dist     = (const float*)d_in[4];
  const float* wbb      = (const float*)d_in[5];
  const float* wff      = (const float*)d_in[6];
  const float* wll      = (const float*)d_in[7];
  const float* lm       = (const float*)d_in[8];
  const float* theta    = (const float*)d_in[9];
  float* out = (float*)d_out;

  float* vsnap = (float*)d_ws;               // TRS*NODE
  float* part  = vsnap + TRS * NODE;         // 3*64 ssq partials

  ssq_kernel<<<64, 256, 0, stream>>>(wbb, wff, wll, sc, part);
  sim_kernel<<<NODE / 2, 128, 0, stream>>>(external, hx, hE, sc, dist, wbb, wff,
                                           wll, theta, part, vsnap);
  eeg_kernel<<<TRS, 256, 0, stream>>>(lm, vsnap, theta, out);
}